// Round 3
// baseline (737.728 us; speedup 1.0000x reference)
//
#include <hip/hip_runtime.h>
#include <math.h>

#define B_  8
#define C_  256
#define NS_ 16384
#define NT_ 8192
#define H_  8
#define D_  32
#define C2_ 512
#define NCH 4
#define KVZ_ (H_*D_*D_ + H_*D_)   // 8448 floats per (batch, chunk)

typedef __attribute__((ext_vector_type(8))) short bf16x8;
typedef __attribute__((ext_vector_type(4))) short bf16x4;
typedef __attribute__((ext_vector_type(4))) float f32x4;

__device__ __forceinline__ short f2bf(float f) {
    unsigned u = __float_as_uint(f);
    u = (u + 0x7fffu + ((u >> 16) & 1u)) >> 16;
    return (short)u;
}
__device__ __forceinline__ float bf2f(short s) {
    return __uint_as_float(((unsigned)(unsigned short)s) << 16);
}
__device__ __forceinline__ float2 bfpair(unsigned u) {
    float2 r;
    r.x = __uint_as_float(u << 16);
    r.y = __uint_as_float(u & 0xffff0000u);
    return r;
}
__device__ __forceinline__ void load_lds16(const void* g, void* l) {
    __builtin_amdgcn_global_load_lds(
        (const __attribute__((address_space(1))) unsigned int*)g,
        (__attribute__((address_space(3))) unsigned int*)l, 16, 0, 0);
}

// ---------------------------------------------------------------------------
// transpose-cast: in [B, C, NLEN] f32 -> ob [G, NLEN, C] bf16
__global__ __launch_bounds__(256)
void castT(const float* __restrict__ in, short* __restrict__ ob, int NLEN, int b0)
{
    __shared__ float tl[32][33];
    int g = blockIdx.z, gb = b0 + g;
    int n0 = blockIdx.x * 32, c0 = blockIdx.y * 32;
    int t = threadIdx.x, tr = t >> 5, tc = t & 31;
    #pragma unroll
    for (int i = 0; i < 4; ++i)
        tl[tr + 8*i][tc] = in[((size_t)gb*C_ + c0 + tr + 8*i)*NLEN + n0 + tc];
    __syncthreads();
    #pragma unroll
    for (int i = 0; i < 4; ++i)
        ob[((size_t)g*NLEN + n0 + tr + 8*i)*C_ + c0 + tc] = f2bf(tl[tc][tr + 8*i]);
}

// ---------------------------------------------------------------------------
// weight transpose-cast: w [K,N] f32 -> wt [N,K] bf16 (7 weights in one launch)
struct WDesc { const float* src; int K; int N; int off; };
struct WPack { WDesc d[7]; };

__global__ __launch_bounds__(256)
void wcast_all(WPack p, short* __restrict__ wt)
{
    __shared__ float tl[32][33];
    WDesc d = p.d[blockIdx.z];
    int kt = blockIdx.x * 32, nt = blockIdx.y * 32;
    if (kt >= d.K || nt >= d.N) return;
    int t = threadIdx.x, tr = t >> 5, tc = t & 31;
    #pragma unroll
    for (int i = 0; i < 4; ++i)
        tl[tr + 8*i][tc] = d.src[(size_t)(kt + tr + 8*i)*d.N + nt + tc];
    __syncthreads();
    short* o = wt + d.off;
    #pragma unroll
    for (int i = 0; i < 4; ++i)
        o[(size_t)(nt + tr + 8*i)*d.K + kt + tc] = f2bf(tl[tc][tr + 8*i]);
}

// ---------------------------------------------------------------------------
// h = relu(xyz @ w1 + b1) -> bf16 [G, NT, C]
__global__ __launch_bounds__(256)
void pos_h(const float* __restrict__ xyz, const float* __restrict__ w1,
           const float* __restrict__ b1, short* __restrict__ hb, int b0)
{
    int g = blockIdx.y, gb = b0 + g;
    int r0 = blockIdx.x * 16;
    int t = threadIdx.x;
    float w1x = w1[t], w1y = w1[C_ + t], w1z = w1[2*C_ + t], bb = b1[t];
    for (int r = 0; r < 16; ++r) {
        const float* p = xyz + ((size_t)gb*NT_ + r0 + r)*3;
        float h = fmaxf(p[0]*w1x + p[1]*w1y + p[2]*w1z + bb, 0.f);
        hb[((size_t)g*NT_ + r0 + r)*C_ + t] = f2bf(h);
    }
}

// ---------------------------------------------------------------------------
// bf16 MFMA GEMM, 128 x (NF*32) tile, BK=32, 4 waves (2x2), 4 x NF fragments.
// A concat: k < split -> A0 (lda0), else A1 (lda1).
// EPI 0: none, 1: relu, 2: elu+1, 3: + bias[col] + addmat[r,col]
template<int EPI, int NF>
__global__ __launch_bounds__(256)
void gemm_bf16(const short* __restrict__ A0, int lda0,
               const short* __restrict__ A1, int lda1, int split,
               const short* __restrict__ Wt,
               const float* __restrict__ bias,
               const short* __restrict__ addmat,
               short* __restrict__ outp,
               int M, int N, int K)
{
    __shared__ __align__(16) short As[128*32];
    __shared__ __align__(16) short Bs[NF*32*32];
    int g = blockIdx.z;
    int nb = blockIdx.x * (NF*32);
    int mb = blockIdx.y * 128;
    int t = threadIdx.x;
    int lane = t & 63;
    int w = t >> 6, wr = w >> 1, wc = w & 1;

    const short* A0g = A0 + (size_t)g*M*lda0;
    const short* A1g = A1 ? (A1 + (size_t)g*M*lda1) : A0;

    f32x4 acc[4][NF] = {};

    int r4 = t >> 2;
    int ch = t & 3;

    for (int kb = 0; kb < K; kb += 32) {
        const short* Ab; int lda, kc;
        if (kb < split) { Ab = A0g; lda = lda0; kc = kb; }
        else            { Ab = A1g; lda = lda1; kc = kb - split; }
        const short* as0 = Ab + (size_t)(mb + r4)*lda + kc + ch*8;
        load_lds16(as0,                   &As[r4*32 + ch*8]);
        load_lds16(as0 + (size_t)64*lda,  &As[(r4 + 64)*32 + ch*8]);
        #pragma unroll
        for (int i = 0; i < NF/2; ++i) {
            int row = r4 + 64*i;
            load_lds16(Wt + (size_t)(nb + row)*K + kb + ch*8, &Bs[row*32 + ch*8]);
        }
        __syncthreads();

        int kq = (lane >> 4) * 8;
        bf16x8 af[4], bfr[NF];
        #pragma unroll
        for (int m = 0; m < 4; ++m)
            af[m] = *(const bf16x8*)&As[(wr*64 + m*16 + (lane & 15))*32 + kq];
        #pragma unroll
        for (int n = 0; n < NF; ++n)
            bfr[n] = *(const bf16x8*)&Bs[(wc*(NF*16) + n*16 + (lane & 15))*32 + kq];
        #pragma unroll
        for (int m = 0; m < 4; ++m)
            #pragma unroll
            for (int n = 0; n < NF; ++n)
                acc[m][n] = __builtin_amdgcn_mfma_f32_16x16x32_bf16(
                    af[m], bfr[n], acc[m][n], 0, 0, 0);
        __syncthreads();
    }

    short* og = outp + (size_t)g*M*N;
    const short* am = (EPI == 3) ? (addmat + (size_t)g*M*N) : nullptr;
    int rq = (lane >> 4) * 4;
    int cl = lane & 15;
    #pragma unroll
    for (int m = 0; m < 4; ++m) {
        #pragma unroll
        for (int r = 0; r < 4; ++r) {
            int row = mb + wr*64 + m*16 + rq + r;
            size_t ro = (size_t)row * N;
            #pragma unroll
            for (int n = 0; n < NF; ++n) {
                int col = nb + wc*(NF*16) + n*16 + cl;
                float v = acc[m][n][r];
                if constexpr (EPI == 1) v = fmaxf(v, 0.f);
                if constexpr (EPI == 2) v = (v > 0.f) ? (v + 1.f) : __expf(v);
                if constexpr (EPI == 3) v = v + bias[col] + bf2f(am[ro + col]);
                og[ro + col] = f2bf(v);
            }
        }
    }
}

// ---------------------------------------------------------------------------
// KV[h,d,vd] partial sums over NT/NCH rows; Ksum[h,d] likewise. grid (H,NCH,G)
__global__ __launch_bounds__(256)
void kv_kernel(const short* __restrict__ Kb, const short* __restrict__ Vb,
               float* __restrict__ kvz)
{
    __shared__ float SK[32][D_];
    __shared__ float SV[32][D_];
    int h = blockIdx.x, chk = blockIdx.y, g = blockIdx.z;
    int t = threadIdx.x;
    int d = t >> 3, v0 = (t & 7) * 4;
    int lr = t >> 3, lc = (t & 7) * 4;
    float acc[4] = {0.f, 0.f, 0.f, 0.f};
    float ksum = 0.f;
    int s0beg = chk * (NT_/NCH), s0end = s0beg + NT_/NCH;
    for (int s0 = s0beg; s0 < s0end; s0 += 32) {
        size_t off = ((size_t)g*NT_ + s0 + lr)*C_ + h*D_ + lc;
        uint2 ku = *(const uint2*)(Kb + off);
        uint2 vu = *(const uint2*)(Vb + off);
        float2 k0 = bfpair(ku.x), k1 = bfpair(ku.y);
        float2 w0 = bfpair(vu.x), w1 = bfpair(vu.y);
        SK[lr][lc] = k0.x; SK[lr][lc+1] = k0.y; SK[lr][lc+2] = k1.x; SK[lr][lc+3] = k1.y;
        SV[lr][lc] = w0.x; SV[lr][lc+1] = w0.y; SV[lr][lc+2] = w1.x; SV[lr][lc+3] = w1.y;
        __syncthreads();
        #pragma unroll
        for (int ss = 0; ss < 32; ++ss) {
            float kd = SK[ss][d];
            #pragma unroll
            for (int j = 0; j < 4; ++j) acc[j] += kd * SV[ss][v0 + j];
            ksum += kd;
        }
        __syncthreads();
    }
    float* KV = kvz + ((size_t)g*NCH + chk)*KVZ_;
    #pragma unroll
    for (int j = 0; j < 4; ++j) KV[h*D_*D_ + d*D_ + v0 + j] = acc[j];
    if ((t & 7) == 0) KV[H_*D_*D_ + h*D_ + d] = ksum;
}

// ---------------------------------------------------------------------------
// reduce NCH partials -> KVT bf16 [G][h][v][d]  +  KSf f32 [G][h][d]. grid (G)
__global__ __launch_bounds__(256)
void kvfin(const float* __restrict__ kvp, short* __restrict__ KVT,
           float* __restrict__ KSf)
{
    int g = blockIdx.x, t = threadIdx.x;
    const float* p = kvp + (size_t)g*NCH*KVZ_;
    for (int idx = t; idx < H_*D_*D_; idx += 256) {
        int h = idx >> 10, rem = idx & 1023, v = rem >> 5, d = rem & 31;
        float s = 0.f;
        #pragma unroll
        for (int c = 0; c < NCH; ++c) s += p[c*KVZ_ + h*1024 + d*32 + v];
        KVT[(size_t)g*8192 + h*1024 + v*32 + d] = f2bf(s);
    }
    {
        float s = 0.f;
        #pragma unroll
        for (int c = 0; c < NCH; ++c) s += p[c*KVZ_ + H_*D_*D_ + t];
        KSf[(size_t)g*256 + t] = s;
    }
}

// ---------------------------------------------------------------------------
// Fused: Q = elu(sf@q_w)+1 ; msg = (Q (x)_h KV) * Z ; mrg = LN1(msg @ merge_w)
// All products computed TRANSPOSED (C rows = channels, cols = sequence l) so
// C-fragments (4 consecutive channels / lane) pack as ds_write_b64 into a
// [l][channel] LDS tile, which is exactly the next phase's B-fragment layout.
// Block: 64 l-rows x 256 channels, 4 waves (wave w owns channels w*64..+63).
__global__ __launch_bounds__(256)
void qam_kernel(const short* __restrict__ sfb, const short* __restrict__ wtq,
                const short* __restrict__ wtm, const short* __restrict__ KVT,
                const float* __restrict__ KSf,
                const float* __restrict__ ln1g, const float* __restrict__ ln1b,
                short* __restrict__ mrg)
{
    __shared__ short QT[64][264];                 // Q, then msg, then LN1 out
    __shared__ __align__(16) short As[64*32];     // sf staging
    __shared__ __align__(16) short Bs[256*32];    // weight staging
    __shared__ float sredS[4][64], sredQ[4][64];
    __shared__ float mrM[64], mrR[64];
    __shared__ float gbet[512];

    int g = blockIdx.y;
    int l0 = blockIdx.x * 64;
    int t = threadIdx.x;
    int lane = t & 63, w = t >> 6;
    int lx = lane & 15, ly = lane >> 4;

    gbet[t]       = ln1g[t];
    gbet[256 + t] = ln1b[t];

    const short* sfg = sfb + ((size_t)g*NS_ + l0)*C_;

    // ---- phase 1: Q^T = Wq^T(A) @ sf^T(B), K=256
    f32x4 acc[4][4] = {};
    for (int kb = 0; kb < C_; kb += 32) {
        load_lds16(sfg + (size_t)(t>>2)*C_ + kb + (t&3)*8, &As[(t>>2)*32 + (t&3)*8]);
        #pragma unroll
        for (int i = 0; i < 4; ++i) {
            int row = (t>>2) + 64*i;
            load_lds16(wtq + (size_t)row*C_ + kb + (t&3)*8, &Bs[row*32 + (t&3)*8]);
        }
        __syncthreads();
        bf16x8 af[4], bfv[4];
        #pragma unroll
        for (int m = 0; m < 4; ++m)
            af[m] = *(const bf16x8*)&Bs[(w*64 + m*16 + lx)*32 + ly*8];
        #pragma unroll
        for (int n = 0; n < 4; ++n)
            bfv[n] = *(const bf16x8*)&As[(n*16 + lx)*32 + ly*8];
        #pragma unroll
        for (int m = 0; m < 4; ++m)
            #pragma unroll
            for (int n = 0; n < 4; ++n)
                acc[m][n] = __builtin_amdgcn_mfma_f32_16x16x32_bf16(
                    af[m], bfv[n], acc[m][n], 0, 0, 0);
        __syncthreads();
    }
    // elu+1, pack into QT[l][c]
    #pragma unroll
    for (int m = 0; m < 4; ++m) {
        int c0 = w*64 + m*16 + ly*4;
        #pragma unroll
        for (int n = 0; n < 4; ++n) {
            bf16x4 pk;
            #pragma unroll
            for (int r = 0; r < 4; ++r) {
                float v = acc[m][n][r];
                pk[r] = f2bf((v > 0.f) ? (v + 1.f) : __expf(v));
            }
            *(bf16x4*)&QT[n*16 + lx][c0] = pk;
        }
    }
    __syncthreads();

    // ---- phase 2: msg^T = KV^T(A) @ Q^T(B), K=32 per head; Z via dot+shfl
    const short* kvg = KVT + (size_t)g*8192;
    bf16x8 bq[2][4];
    #pragma unroll
    for (int hh = 0; hh < 2; ++hh)
        #pragma unroll
        for (int n = 0; n < 4; ++n)
            bq[hh][n] = *(const bf16x8*)&QT[n*16 + lx][(2*w + hh)*32 + ly*8];
    float z[2][4];
    #pragma unroll
    for (int hh = 0; hh < 2; ++hh) {
        const float* kp = KSf + (size_t)g*256 + (2*w + hh)*32 + ly*8;
        float4 ka = *(const float4*)kp;
        float4 kb4 = *(const float4*)(kp + 4);
        float kr[8] = {ka.x, ka.y, ka.z, ka.w, kb4.x, kb4.y, kb4.z, kb4.w};
        #pragma unroll
        for (int n = 0; n < 4; ++n) {
            float s = 0.f;
            #pragma unroll
            for (int j = 0; j < 8; ++j) s += bf2f(bq[hh][n][j]) * kr[j];
            s += __shfl_xor(s, 16);
            s += __shfl_xor(s, 32);
            z[hh][n] = 1.f / (s + 1e-6f);
        }
    }
    f32x4 zero = {0.f, 0.f, 0.f, 0.f};
    f32x4 a2[4][4];
    #pragma unroll
    for (int m = 0; m < 4; ++m) {
        int h = 2*w + (m >> 1);
        bf16x8 afk = *(const bf16x8*)(kvg + ((size_t)h*1024 + ((m&1)*16 + lx)*32 + ly*8));
        #pragma unroll
        for (int n = 0; n < 4; ++n)
            a2[m][n] = __builtin_amdgcn_mfma_f32_16x16x32_bf16(
                afk, bq[m>>1][n], zero, 0, 0, 0);
    }
    #pragma unroll
    for (int m = 0; m < 4; ++m) {
        int c0 = w*64 + m*16 + ly*4;
        #pragma unroll
        for (int n = 0; n < 4; ++n) {
            bf16x4 pk;
            #pragma unroll
            for (int r = 0; r < 4; ++r)
                pk[r] = f2bf(a2[m][n][r] * z[m>>1][n]);
            *(bf16x4*)&QT[n*16 + lx][c0] = pk;
        }
    }
    __syncthreads();

    // ---- phase 3: mrg^T = Wm^T(A) @ msg^T(B), K=256
    f32x4 acc3[4][4] = {};
    for (int kb = 0; kb < C_; kb += 32) {
        #pragma unroll
        for (int i = 0; i < 4; ++i) {
            int row = (t>>2) + 64*i;
            load_lds16(wtm + (size_t)row*C_ + kb + (t&3)*8, &Bs[row*32 + (t&3)*8]);
        }
        __syncthreads();
        bf16x8 af[4], bfv[4];
        #pragma unroll
        for (int m = 0; m < 4; ++m)
            af[m] = *(const bf16x8*)&Bs[(w*64 + m*16 + lx)*32 + ly*8];
        #pragma unroll
        for (int n = 0; n < 4; ++n)
            bfv[n] = *(const bf16x8*)&QT[n*16 + lx][kb + ly*8];
        #pragma unroll
        for (int m = 0; m < 4; ++m)
            #pragma unroll
            for (int n = 0; n < 4; ++n)
                acc3[m][n] = __builtin_amdgcn_mfma_f32_16x16x32_bf16(
                    af[m], bfv[n], acc3[m][n], 0, 0, 0);
        __syncthreads();
    }

    // ---- LN1 over channels (f32 accs): partials per l, reduce waves in LDS
    float sP[4] = {0,0,0,0}, qP[4] = {0,0,0,0};
    #pragma unroll
    for (int n = 0; n < 4; ++n)
        #pragma unroll
        for (int m = 0; m < 4; ++m)
            #pragma unroll
            for (int r = 0; r < 4; ++r) {
                float v = acc3[m][n][r];
                sP[n] += v; qP[n] += v*v;
            }
    #pragma unroll
    for (int n = 0; n < 4; ++n) {
        sP[n] += __shfl_xor(sP[n], 16); sP[n] += __shfl_xor(sP[n], 32);
        qP[n] += __shfl_xor(qP[n], 16); qP[n] += __shfl_xor(qP[n], 32);
    }
    if (ly == 0) {
        #pragma unroll
        for (int n = 0; n < 4; ++n) {
            sredS[w][n*16 + lx] = sP[n];
            sredQ[w][n*16 + lx] = qP[n];
        }
    }
    __syncthreads();
    if (t < 64) {
        float s = 0.f, q = 0.f;
        #pragma unroll
        for (int ww = 0; ww < 4; ++ww) { s += sredS[ww][t]; q += sredQ[ww][t]; }
        float m = s * (1.f/C_);
        mrM[t] = m;
        mrR[t] = rsqrtf(q*(1.f/C_) - m*m + 1e-5f);
    }
    __syncthreads();
    #pragma unroll
    for (int n = 0; n < 4; ++n) {
        float mn = mrM[n*16 + lx], rs = mrR[n*16 + lx];
        #pragma unroll
        for (int m = 0; m < 4; ++m) {
            int c0 = w*64 + m*16 + ly*4;
            bf16x4 pk;
            #pragma unroll
            for (int r = 0; r < 4; ++r) {
                int c = c0 + r;
                pk[r] = f2bf((acc3[m][n][r] - mn)*rs*gbet[c] + gbet[256 + c]);
            }
            *(bf16x4*)&QT[n*16 + lx][c0] = pk;
        }
    }
    __syncthreads();
    // coalesced copy-out
    short* og = mrg + ((size_t)g*NS_ + l0)*C_;
    int row = t >> 2;
    #pragma unroll
    for (int i = 0; i < 8; ++i) {
        int chk = (t & 3) + 4*i;
        *(uint4*)(og + (size_t)row*C_ + chk*8) = *(const uint4*)&QT[row][chk*8];
    }
}

// ---------------------------------------------------------------------------
// out[b,c,l] = sfeat[b,c,l] + LN2(m2[g,l,:])[c]. grid (NS/32, G)
__global__ __launch_bounds__(256)
void final_kernel(const short* __restrict__ m2, const float* __restrict__ sfeat,
                  const float* __restrict__ gam, const float* __restrict__ bet,
                  float* __restrict__ out, int b0)
{
    __shared__ float ms2[32][C_ + 4];
    __shared__ float reds[8][32], redq[8][32];
    __shared__ float mean_s[32], rstd_s[32];
    int g = blockIdx.y, gb = b0 + g;
    int l0 = blockIdx.x * 32;
    int t = threadIdx.x;
    {
        int r = t >> 3, c0 = (t & 7) * 8;
        const short* row = m2 + ((size_t)g*NS_ + l0 + r)*C_;
        #pragma unroll
        for (int j = 0; j < 4; ++j) {
            uint4 p = *(const uint4*)(row + c0 + 64*j);
            float2 f0 = bfpair(p.x), f1 = bfpair(p.y), f2 = bfpair(p.z), f3 = bfpair(p.w);
            int cb = c0 + 64*j;
            ms2[r][cb+0] = f0.x; ms2[r][cb+1] = f0.y;
            ms2[r][cb+2] = f1.x; ms2[r][cb+3] = f1.y;
            ms2[r][cb+4] = f2.x; ms2[r][cb+5] = f2.y;
            ms2[r][cb+6] = f3.x; ms2[r][cb+7] = f3.y;
        }
    }
    __syncthreads();
    {
        int rr = t & 31, part = t >> 5;
        float s = 0.f, q = 0.f;
        #pragma unroll
        for (int j = 0; j < 32; ++j) {
            float v = ms2[rr][part*32 + j];
            s += v; q += v*v;
        }
        reds[part][rr] = s; redq[part][rr] = q;
    }
    __syncthreads();
    if (t < 32) {
        float s = 0.f, q = 0.f;
        #pragma unroll
        for (int p = 0; p < 8; ++p) { s += reds[p][t]; q += redq[p][t]; }
        float m = s * (1.f/C_);
        mean_s[t] = m;
        rstd_s[t] = rsqrtf(q*(1.f/C_) - m*m + 1e-5f);
    }
    __syncthreads();
    int li = t & 31, cg = t >> 5;
    float mn = mean_s[li], rs = rstd_s[li];
    for (int cc = 0; cc < 32; ++cc) {
        int c = cg + 8*cc;
        size_t o = ((size_t)gb*C_ + c)*NS_ + l0 + li;
        out[o] = sfeat[o] + (ms2[li][c] - mn)*rs*gam[c] + bet[c];
    }
}

// ---------------------------------------------------------------------------
extern "C" void kernel_launch(void* const* d_in, const int* in_sizes, int n_in,
                              void* d_out, int out_size, void* d_ws, size_t ws_size,
                              hipStream_t stream)
{
    (void)in_sizes; (void)n_in; (void)out_size;
    const float* search_feat   = (const float*)d_in[0];
    const float* template_feat = (const float*)d_in[2];
    const float* template_xyz  = (const float*)d_in[3];
    const float* pos_w1  = (const float*)d_in[4];
    const float* pos_b1  = (const float*)d_in[5];
    const float* pos_w2  = (const float*)d_in[6];
    const float* pos_b2  = (const float*)d_in[7];
    const float* q_w     = (const float*)d_in[8];
    const float* k_w     = (const float*)d_in[9];
    const float* v_w     = (const float*)d_in[10];
    const float* merge_w = (const float*)d_in[11];
    const float* mlp_w1  = (const float*)d_in[12];
    const float* mlp_w2  = (const float*)d_in[13];
    const float* ln1_g   = (const float*)d_in[14];
    const float* ln1_b   = (const float*)d_in[15];
    const float* ln2_g   = (const float*)d_in[16];
    const float* ln2_b   = (const float*)d_in[17];
    float* out = (float*)d_out;

    const int W_Q = 0, W_K = 65536, W_V = 131072, W_M = 196608,
              W_P = 262144, W_1 = 327680, W_2 = 589824;
    const size_t wElems = 720896;

    size_t sfE = (size_t)NS_*C_, tfE = (size_t)NT_*C_;
    int G = 8;
    while (G > 1) {
        size_t shorts = (size_t)G*(5*sfE + 2*tfE) + wElems + (size_t)G*8192;
        size_t bytes  = shorts*2 + (size_t)G*NCH*KVZ_*4 + (size_t)G*256*4 + 512;
        if (bytes <= ws_size) break;
        G >>= 1;
    }

    short* wtb  = (short*)d_ws;
    short* sfb  = wtb  + wElems;          // [G,NS,C]
    short* tfb  = sfb  + (size_t)G*sfE;   // [G,NT,C]
    short* tfpb = tfb  + (size_t)G*tfE;   // [G,NT,C]
    short* hid  = tfpb + (size_t)G*tfE;   // [G,NS,2C]; earlier K|V
    short* mrgb = hid  + (size_t)2*G*sfE; // [G,NS,C]  LN1(merge) out
    short* m2b  = mrgb + (size_t)G*sfE;   // [G,NS,C]  pos-h, then mlp2 out
    short* KVTb = m2b  + (size_t)G*sfE;   // [G,8192]
    float* kvpf = (float*)(KVTb + (size_t)G*8192);
    float* KSfb = kvpf + (size_t)G*NCH*KVZ_;
    short* Kb = hid;
    short* Vb = hid + (size_t)G*tfE;

    WPack pack;
    pack.d[0] = { q_w,     C_,  C_,  W_Q };
    pack.d[1] = { k_w,     C_,  C_,  W_K };
    pack.d[2] = { v_w,     C_,  C_,  W_V };
    pack.d[3] = { merge_w, C_,  C_,  W_M };
    pack.d[4] = { pos_w2,  C_,  C_,  W_P };
    pack.d[5] = { mlp_w1,  C2_, C2_, W_1 };
    pack.d[6] = { mlp_w2,  C2_, C_,  W_2 };
    wcast_all<<<dim3(16, 16, 7), 256, 0, stream>>>(pack, wtb);

    for (int b0 = 0; b0 < B_; b0 += G) {
        castT<<<dim3(NS_/32, C_/32, G), 256, 0, stream>>>(search_feat, sfb, NS_, b0);
        castT<<<dim3(NT_/32, C_/32, G), 256, 0, stream>>>(template_feat, tfb, NT_, b0);
        pos_h<<<dim3(NT_/16, G), 256, 0, stream>>>(template_xyz, pos_w1, pos_b1, m2b, b0);
        // tfp = h @ posw2 + b2 + tf
        gemm_bf16<3,8><<<dim3(1, NT_/128, G), 256, 0, stream>>>(
            m2b, C_, nullptr, 0, 1<<30, wtb + W_P, pos_b2, tfb, tfpb, NT_, C_, C_);
        // K = elu(tf @ k_w)+1
        gemm_bf16<2,8><<<dim3(1, NT_/128, G), 256, 0, stream>>>(
            tfb, C_, nullptr, 0, 1<<30, wtb + W_K, nullptr, nullptr, Kb, NT_, C_, C_);
        // V = tfp @ v_w
        gemm_bf16<0,8><<<dim3(1, NT_/128, G), 256, 0, stream>>>(
            tfpb, C_, nullptr, 0, 1<<30, wtb + W_V, nullptr, nullptr, Vb, NT_, C_, C_);
        kv_kernel<<<dim3(H_, NCH, G), 256, 0, stream>>>(Kb, Vb, kvpf);
        kvfin<<<dim3(G), 256, 0, stream>>>(kvpf, KVTb, KSfb);
        // fused Q -> attn -> merge -> LN1
        qam_kernel<<<dim3(NS_/64, G), 256, 0, stream>>>(
            sfb, wtb + W_Q, wtb + W_M, KVTb, KSfb, ln1_g, ln1_b, mrgb);
        // hidden = relu([sf | mrg] @ mlp_w1)
        gemm_bf16<1,8><<<dim3(2, NS_/128, G), 256, 0, stream>>>(
            sfb, C_, mrgb, C_, C_, wtb + W_1, nullptr, nullptr, hid, NS_, C2_, C2_);
        // m2 = hidden @ mlp_w2
        gemm_bf16<0,8><<<dim3(1, NS_/128, G), 256, 0, stream>>>(
            hid, C2_, nullptr, 0, 1<<30, wtb + W_2, nullptr, nullptr, m2b, NS_, C_, C2_);
        final_kernel<<<dim3(NS_/32, G), 256, 0, stream>>>(
            m2b, search_feat, ln2_g, ln2_b, out, b0);
    }
}

// Round 4
// 601.468 us; speedup vs baseline: 1.2265x; 1.2265x over previous
//
#include <hip/hip_runtime.h>
#include <math.h>

#define B_  8
#define C_  256
#define NS_ 16384
#define NT_ 8192
#define H_  8
#define D_  32
#define C2_ 512
#define NCH 4
#define KVZ_ (H_*D_*D_ + H_*D_)   // 8448 floats per (batch, chunk)

typedef __attribute__((ext_vector_type(8))) short bf16x8;
typedef __attribute__((ext_vector_type(4))) short bf16x4;
typedef __attribute__((ext_vector_type(4))) float f32x4;

__device__ __forceinline__ short f2bf(float f) {
    unsigned u = __float_as_uint(f);
    u = (u + 0x7fffu + ((u >> 16) & 1u)) >> 16;
    return (short)u;
}
__device__ __forceinline__ float bf2f(short s) {
    return __uint_as_float(((unsigned)(unsigned short)s) << 16);
}
__device__ __forceinline__ float2 bfpair(unsigned u) {
    float2 r;
    r.x = __uint_as_float(u << 16);
    r.y = __uint_as_float(u & 0xffff0000u);
    return r;
}
__device__ __forceinline__ void load_lds16(const void* g, void* l) {
    __builtin_amdgcn_global_load_lds(
        (const __attribute__((address_space(1))) unsigned int*)g,
        (__attribute__((address_space(3))) unsigned int*)l, 16, 0, 0);
}

// ---------------------------------------------------------------------------
// transpose-cast: in [B, C, NLEN] f32 -> ob [G, NLEN, C] bf16
__global__ __launch_bounds__(256)
void castT(const float* __restrict__ in, short* __restrict__ ob, int NLEN, int b0)
{
    __shared__ float tl[32][33];
    int g = blockIdx.z, gb = b0 + g;
    int n0 = blockIdx.x * 32, c0 = blockIdx.y * 32;
    int t = threadIdx.x, tr = t >> 5, tc = t & 31;
    #pragma unroll
    for (int i = 0; i < 4; ++i)
        tl[tr + 8*i][tc] = in[((size_t)gb*C_ + c0 + tr + 8*i)*NLEN + n0 + tc];
    __syncthreads();
    #pragma unroll
    for (int i = 0; i < 4; ++i)
        ob[((size_t)g*NLEN + n0 + tr + 8*i)*C_ + c0 + tc] = f2bf(tl[tc][tr + 8*i]);
}

// ---------------------------------------------------------------------------
// weight transpose-cast: w [K,N] f32 -> wt [N,K] bf16 (7 weights in one launch)
struct WDesc { const float* src; int K; int N; int off; };
struct WPack { WDesc d[7]; };

__global__ __launch_bounds__(256)
void wcast_all(WPack p, short* __restrict__ wt)
{
    __shared__ float tl[32][33];
    WDesc d = p.d[blockIdx.z];
    int kt = blockIdx.x * 32, nt = blockIdx.y * 32;
    if (kt >= d.K || nt >= d.N) return;
    int t = threadIdx.x, tr = t >> 5, tc = t & 31;
    #pragma unroll
    for (int i = 0; i < 4; ++i)
        tl[tr + 8*i][tc] = d.src[(size_t)(kt + tr + 8*i)*d.N + nt + tc];
    __syncthreads();
    short* o = wt + d.off;
    #pragma unroll
    for (int i = 0; i < 4; ++i)
        o[(size_t)(nt + tr + 8*i)*d.K + kt + tc] = f2bf(tl[tc][tr + 8*i]);
}

// ---------------------------------------------------------------------------
// h = relu(xyz @ w1 + b1) -> bf16 [G, NT, C]
__global__ __launch_bounds__(256)
void pos_h(const float* __restrict__ xyz, const float* __restrict__ w1,
           const float* __restrict__ b1, short* __restrict__ hb, int b0)
{
    int g = blockIdx.y, gb = b0 + g;
    int r0 = blockIdx.x * 16;
    int t = threadIdx.x;
    float w1x = w1[t], w1y = w1[C_ + t], w1z = w1[2*C_ + t], bb = b1[t];
    for (int r = 0; r < 16; ++r) {
        const float* p = xyz + ((size_t)gb*NT_ + r0 + r)*3;
        float h = fmaxf(p[0]*w1x + p[1]*w1y + p[2]*w1z + bb, 0.f);
        hb[((size_t)g*NT_ + r0 + r)*C_ + t] = f2bf(h);
    }
}

// ---------------------------------------------------------------------------
// bf16 MFMA GEMM, 128 x (NF*32) tile, BK=32, 4 waves (2x2), 4 x NF fragments.
// NF=4 (128x128): VGPR ~68, ~31% occupancy — the proven config (round 2).
// A concat: k < split -> A0 (lda0), else A1 (lda1).
// EPI 0: none, 1: relu, 2: elu+1, 3: + bias[col] + addmat[r,col]
template<int EPI, int NF>
__global__ __launch_bounds__(256)
void gemm_bf16(const short* __restrict__ A0, int lda0,
               const short* __restrict__ A1, int lda1, int split,
               const short* __restrict__ Wt,
               const float* __restrict__ bias,
               const short* __restrict__ addmat,
               short* __restrict__ outp,
               int M, int N, int K)
{
    __shared__ __align__(16) short As[128*32];
    __shared__ __align__(16) short Bs[NF*32*32];
    int g = blockIdx.z;
    int nb = blockIdx.x * (NF*32);
    int mb = blockIdx.y * 128;
    int t = threadIdx.x;
    int lane = t & 63;
    int w = t >> 6, wr = w >> 1, wc = w & 1;

    const short* A0g = A0 + (size_t)g*M*lda0;
    const short* A1g = A1 ? (A1 + (size_t)g*M*lda1) : A0;

    f32x4 acc[4][NF] = {};

    int r4 = t >> 2;
    int ch = t & 3;

    for (int kb = 0; kb < K; kb += 32) {
        const short* Ab; int lda, kc;
        if (kb < split) { Ab = A0g; lda = lda0; kc = kb; }
        else            { Ab = A1g; lda = lda1; kc = kb - split; }
        const short* as0 = Ab + (size_t)(mb + r4)*lda + kc + ch*8;
        load_lds16(as0,                   &As[r4*32 + ch*8]);
        load_lds16(as0 + (size_t)64*lda,  &As[(r4 + 64)*32 + ch*8]);
        #pragma unroll
        for (int i = 0; i < NF/2; ++i) {
            int row = r4 + 64*i;
            load_lds16(Wt + (size_t)(nb + row)*K + kb + ch*8, &Bs[row*32 + ch*8]);
        }
        __syncthreads();

        int kq = (lane >> 4) * 8;
        bf16x8 af[4], bfr[NF];
        #pragma unroll
        for (int m = 0; m < 4; ++m)
            af[m] = *(const bf16x8*)&As[(wr*64 + m*16 + (lane & 15))*32 + kq];
        #pragma unroll
        for (int n = 0; n < NF; ++n)
            bfr[n] = *(const bf16x8*)&Bs[(wc*(NF*16) + n*16 + (lane & 15))*32 + kq];
        #pragma unroll
        for (int m = 0; m < 4; ++m)
            #pragma unroll
            for (int n = 0; n < NF; ++n)
                acc[m][n] = __builtin_amdgcn_mfma_f32_16x16x32_bf16(
                    af[m], bfr[n], acc[m][n], 0, 0, 0);
        __syncthreads();
    }

    short* og = outp + (size_t)g*M*N;
    const short* am = (EPI == 3) ? (addmat + (size_t)g*M*N) : nullptr;
    int rq = (lane >> 4) * 4;
    int cl = lane & 15;
    #pragma unroll
    for (int m = 0; m < 4; ++m) {
        #pragma unroll
        for (int r = 0; r < 4; ++r) {
            int row = mb + wr*64 + m*16 + rq + r;
            size_t ro = (size_t)row * N;
            #pragma unroll
            for (int n = 0; n < NF; ++n) {
                int col = nb + wc*(NF*16) + n*16 + cl;
                float v = acc[m][n][r];
                if constexpr (EPI == 1) v = fmaxf(v, 0.f);
                if constexpr (EPI == 2) v = (v > 0.f) ? (v + 1.f) : __expf(v);
                if constexpr (EPI == 3) v = v + bias[col] + bf2f(am[ro + col]);
                og[ro + col] = f2bf(v);
            }
        }
    }
}

// ---------------------------------------------------------------------------
// KV[h,d,vd] partial sums over NT/NCH rows; Ksum[h,d] likewise. grid (H,NCH,G)
__global__ __launch_bounds__(256)
void kv_kernel(const short* __restrict__ Kb, const short* __restrict__ Vb,
               float* __restrict__ kvz)
{
    __shared__ float SK[32][D_];
    __shared__ float SV[32][D_];
    int h = blockIdx.x, chk = blockIdx.y, g = blockIdx.z;
    int t = threadIdx.x;
    int d = t >> 3, v0 = (t & 7) * 4;
    int lr = t >> 3, lc = (t & 7) * 4;
    float acc[4] = {0.f, 0.f, 0.f, 0.f};
    float ksum = 0.f;
    int s0beg = chk * (NT_/NCH), s0end = s0beg + NT_/NCH;
    for (int s0 = s0beg; s0 < s0end; s0 += 32) {
        size_t off = ((size_t)g*NT_ + s0 + lr)*C_ + h*D_ + lc;
        uint2 ku = *(const uint2*)(Kb + off);
        uint2 vu = *(const uint2*)(Vb + off);
        float2 k0 = bfpair(ku.x), k1 = bfpair(ku.y);
        float2 w0 = bfpair(vu.x), w1 = bfpair(vu.y);
        SK[lr][lc] = k0.x; SK[lr][lc+1] = k0.y; SK[lr][lc+2] = k1.x; SK[lr][lc+3] = k1.y;
        SV[lr][lc] = w0.x; SV[lr][lc+1] = w0.y; SV[lr][lc+2] = w1.x; SV[lr][lc+3] = w1.y;
        __syncthreads();
        #pragma unroll
        for (int ss = 0; ss < 32; ++ss) {
            float kd = SK[ss][d];
            #pragma unroll
            for (int j = 0; j < 4; ++j) acc[j] += kd * SV[ss][v0 + j];
            ksum += kd;
        }
        __syncthreads();
    }
    float* KV = kvz + ((size_t)g*NCH + chk)*KVZ_;
    #pragma unroll
    for (int j = 0; j < 4; ++j) KV[h*D_*D_ + d*D_ + v0 + j] = acc[j];
    if ((t & 7) == 0) KV[H_*D_*D_ + h*D_ + d] = ksum;
}

// ---------------------------------------------------------------------------
// reduce NCH partials -> KVT bf16 [G][h][v][d]  +  KSf f32 [G][h][d]. grid (G)
__global__ __launch_bounds__(256)
void kvfin(const float* __restrict__ kvp, short* __restrict__ KVT,
           float* __restrict__ KSf)
{
    int g = blockIdx.x, t = threadIdx.x;
    const float* p = kvp + (size_t)g*NCH*KVZ_;
    for (int idx = t; idx < H_*D_*D_; idx += 256) {
        int h = idx >> 10, rem = idx & 1023, v = rem >> 5, d = rem & 31;
        float s = 0.f;
        #pragma unroll
        for (int c = 0; c < NCH; ++c) s += p[c*KVZ_ + h*1024 + d*32 + v];
        KVT[(size_t)g*8192 + h*1024 + v*32 + d] = f2bf(s);
    }
    {
        float s = 0.f;
        #pragma unroll
        for (int c = 0; c < NCH; ++c) s += p[c*KVZ_ + H_*D_*D_ + t];
        KSf[(size_t)g*256 + t] = s;
    }
}

// ---------------------------------------------------------------------------
// Fused: Q = elu(sf@q_w)+1 ; msg = (Q (x)_h KV) * Z ; mrg = LN1(msg @ merge_w)
// All products computed TRANSPOSED (C rows = channels, cols = sequence l).
__global__ __launch_bounds__(256)
void qam_kernel(const short* __restrict__ sfb, const short* __restrict__ wtq,
                const short* __restrict__ wtm, const short* __restrict__ KVT,
                const float* __restrict__ KSf,
                const float* __restrict__ ln1g, const float* __restrict__ ln1b,
                short* __restrict__ mrg)
{
    __shared__ short QT[64][264];                 // Q, then msg, then LN1 out
    __shared__ __align__(16) short As[64*32];     // sf staging
    __shared__ __align__(16) short Bs[256*32];    // weight staging
    __shared__ float sredS[4][64], sredQ[4][64];
    __shared__ float mrM[64], mrR[64];
    __shared__ float gbet[512];

    int g = blockIdx.y;
    int l0 = blockIdx.x * 64;
    int t = threadIdx.x;
    int lane = t & 63, w = t >> 6;
    int lx = lane & 15, ly = lane >> 4;

    gbet[t]       = ln1g[t];
    gbet[256 + t] = ln1b[t];

    const short* sfg = sfb + ((size_t)g*NS_ + l0)*C_;

    // ---- phase 1: Q^T = Wq^T(A) @ sf^T(B), K=256
    f32x4 acc[4][4] = {};
    for (int kb = 0; kb < C_; kb += 32) {
        load_lds16(sfg + (size_t)(t>>2)*C_ + kb + (t&3)*8, &As[(t>>2)*32 + (t&3)*8]);
        #pragma unroll
        for (int i = 0; i < 4; ++i) {
            int row = (t>>2) + 64*i;
            load_lds16(wtq + (size_t)row*C_ + kb + (t&3)*8, &Bs[row*32 + (t&3)*8]);
        }
        __syncthreads();
        bf16x8 af[4], bfv[4];
        #pragma unroll
        for (int m = 0; m < 4; ++m)
            af[m] = *(const bf16x8*)&Bs[(w*64 + m*16 + lx)*32 + ly*8];
        #pragma unroll
        for (int n = 0; n < 4; ++n)
            bfv[n] = *(const bf16x8*)&As[(n*16 + lx)*32 + ly*8];
        #pragma unroll
        for (int m = 0; m < 4; ++m)
            #pragma unroll
            for (int n = 0; n < 4; ++n)
                acc[m][n] = __builtin_amdgcn_mfma_f32_16x16x32_bf16(
                    af[m], bfv[n], acc[m][n], 0, 0, 0);
        __syncthreads();
    }
    #pragma unroll
    for (int m = 0; m < 4; ++m) {
        int c0 = w*64 + m*16 + ly*4;
        #pragma unroll
        for (int n = 0; n < 4; ++n) {
            bf16x4 pk;
            #pragma unroll
            for (int r = 0; r < 4; ++r) {
                float v = acc[m][n][r];
                pk[r] = f2bf((v > 0.f) ? (v + 1.f) : __expf(v));
            }
            *(bf16x4*)&QT[n*16 + lx][c0] = pk;
        }
    }
    __syncthreads();

    // ---- phase 2: msg^T = KV^T(A) @ Q^T(B), K=32 per head; Z via dot+shfl
    const short* kvg = KVT + (size_t)g*8192;
    bf16x8 bq[2][4];
    #pragma unroll
    for (int hh = 0; hh < 2; ++hh)
        #pragma unroll
        for (int n = 0; n < 4; ++n)
            bq[hh][n] = *(const bf16x8*)&QT[n*16 + lx][(2*w + hh)*32 + ly*8];
    float z[2][4];
    #pragma unroll
    for (int hh = 0; hh < 2; ++hh) {
        const float* kp = KSf + (size_t)g*256 + (2*w + hh)*32 + ly*8;
        float4 ka = *(const float4*)kp;
        float4 kb4 = *(const float4*)(kp + 4);
        float kr[8] = {ka.x, ka.y, ka.z, ka.w, kb4.x, kb4.y, kb4.z, kb4.w};
        #pragma unroll
        for (int n = 0; n < 4; ++n) {
            float s = 0.f;
            #pragma unroll
            for (int j = 0; j < 8; ++j) s += bf2f(bq[hh][n][j]) * kr[j];
            s += __shfl_xor(s, 16);
            s += __shfl_xor(s, 32);
            z[hh][n] = 1.f / (s + 1e-6f);
        }
    }
    f32x4 zero = {0.f, 0.f, 0.f, 0.f};
    f32x4 a2[4][4];
    #pragma unroll
    for (int m = 0; m < 4; ++m) {
        int h = 2*w + (m >> 1);
        bf16x8 afk = *(const bf16x8*)(kvg + ((size_t)h*1024 + ((m&1)*16 + lx)*32 + ly*8));
        #pragma unroll
        for (int n = 0; n < 4; ++n)
            a2[m][n] = __builtin_amdgcn_mfma_f32_16x16x32_bf16(
                afk, bq[m>>1][n], zero, 0, 0, 0);
    }
    #pragma unroll
    for (int m = 0; m < 4; ++m) {
        int c0 = w*64 + m*16 + ly*4;
        #pragma unroll
        for (int n = 0; n < 4; ++n) {
            bf16x4 pk;
            #pragma unroll
            for (int r = 0; r < 4; ++r)
                pk[r] = f2bf(a2[m][n][r] * z[m>>1][n]);
            *(bf16x4*)&QT[n*16 + lx][c0] = pk;
        }
    }
    __syncthreads();

    // ---- phase 3: mrg^T = Wm^T(A) @ msg^T(B), K=256
    f32x4 acc3[4][4] = {};
    for (int kb = 0; kb < C_; kb += 32) {
        #pragma unroll
        for (int i = 0; i < 4; ++i) {
            int row = (t>>2) + 64*i;
            load_lds16(wtm + (size_t)row*C_ + kb + (t&3)*8, &Bs[row*32 + (t&3)*8]);
        }
        __syncthreads();
        bf16x8 af[4], bfv[4];
        #pragma unroll
        for (int m = 0; m < 4; ++m)
            af[m] = *(const bf16x8*)&Bs[(w*64 + m*16 + lx)*32 + ly*8];
        #pragma unroll
        for (int n = 0; n < 4; ++n)
            bfv[n] = *(const bf16x8*)&QT[n*16 + lx][kb + ly*8];
        #pragma unroll
        for (int m = 0; m < 4; ++m)
            #pragma unroll
            for (int n = 0; n < 4; ++n)
                acc3[m][n] = __builtin_amdgcn_mfma_f32_16x16x32_bf16(
                    af[m], bfv[n], acc3[m][n], 0, 0, 0);
        __syncthreads();
    }

    // ---- LN1 over channels (f32 accs)
    float sP[4] = {0,0,0,0}, qP[4] = {0,0,0,0};
    #pragma unroll
    for (int n = 0; n < 4; ++n)
        #pragma unroll
        for (int m = 0; m < 4; ++m)
            #pragma unroll
            for (int r = 0; r < 4; ++r) {
                float v = acc3[m][n][r];
                sP[n] += v; qP[n] += v*v;
            }
    #pragma unroll
    for (int n = 0; n < 4; ++n) {
        sP[n] += __shfl_xor(sP[n], 16); sP[n] += __shfl_xor(sP[n], 32);
        qP[n] += __shfl_xor(qP[n], 16); qP[n] += __shfl_xor(qP[n], 32);
    }
    if (ly == 0) {
        #pragma unroll
        for (int n = 0; n < 4; ++n) {
            sredS[w][n*16 + lx] = sP[n];
            sredQ[w][n*16 + lx] = qP[n];
        }
    }
    __syncthreads();
    if (t < 64) {
        float s = 0.f, q = 0.f;
        #pragma unroll
        for (int ww = 0; ww < 4; ++ww) { s += sredS[ww][t]; q += sredQ[ww][t]; }
        float m = s * (1.f/C_);
        mrM[t] = m;
        mrR[t] = rsqrtf(q*(1.f/C_) - m*m + 1e-5f);
    }
    __syncthreads();
    #pragma unroll
    for (int n = 0; n < 4; ++n) {
        float mn = mrM[n*16 + lx], rs = mrR[n*16 + lx];
        #pragma unroll
        for (int m = 0; m < 4; ++m) {
            int c0 = w*64 + m*16 + ly*4;
            bf16x4 pk;
            #pragma unroll
            for (int r = 0; r < 4; ++r) {
                int c = c0 + r;
                pk[r] = f2bf((acc3[m][n][r] - mn)*rs*gbet[c] + gbet[256 + c]);
            }
            *(bf16x4*)&QT[n*16 + lx][c0] = pk;
        }
    }
    __syncthreads();
    short* og = mrg + ((size_t)g*NS_ + l0)*C_;
    int row = t >> 2;
    #pragma unroll
    for (int i = 0; i < 8; ++i) {
        int chk = (t & 3) + 4*i;
        *(uint4*)(og + (size_t)row*C_ + chk*8) = *(const uint4*)&QT[row][chk*8];
    }
}

// ---------------------------------------------------------------------------
// Fused mlp2 + LN2 + residual + transpose:
// m2^T = W2t(A: 256 out-ch rows, K=512) @ hidden^T(B: hidden row-major).
// C-fragment rows = out-channels c, cols = l -> matches out [b,c,l] directly.
// grid (NS/64, G), 4 waves; wave w owns channels w*64..+63.
__global__ __launch_bounds__(256)
void m2f_kernel(const short* __restrict__ hid, const short* __restrict__ wt2,
                const float* __restrict__ sfeat,
                const float* __restrict__ ln2g, const float* __restrict__ ln2b,
                float* __restrict__ out, int b0)
{
    __shared__ __align__(16) short As[256*32];   // W2t tile 256 x 32
    __shared__ __align__(16) short Bs[64*32];    // hidden tile 64 x 32
    __shared__ float sredS[4][64], sredQ[4][64];
    __shared__ float mrM[64], mrR[64];
    __shared__ float gbet[512];

    int g = blockIdx.y, gb = b0 + g;
    int l0 = blockIdx.x * 64;
    int t = threadIdx.x;
    int lane = t & 63, w = t >> 6;
    int lx = lane & 15, ly = lane >> 4;

    gbet[t]       = ln2g[t];
    gbet[256 + t] = ln2b[t];

    const short* hg = hid + ((size_t)g*NS_ + l0)*C2_;
    f32x4 acc[4][4] = {};
    for (int kb = 0; kb < C2_; kb += 32) {
        #pragma unroll
        for (int i = 0; i < 4; ++i) {
            int row = (t>>2) + 64*i;
            load_lds16(wt2 + (size_t)row*C2_ + kb + (t&3)*8, &As[row*32 + (t&3)*8]);
        }
        load_lds16(hg + (size_t)(t>>2)*C2_ + kb + (t&3)*8, &Bs[(t>>2)*32 + (t&3)*8]);
        __syncthreads();
        bf16x8 af[4], bfv[4];
        #pragma unroll
        for (int m = 0; m < 4; ++m)
            af[m] = *(const bf16x8*)&As[(w*64 + m*16 + lx)*32 + ly*8];
        #pragma unroll
        for (int n = 0; n < 4; ++n)
            bfv[n] = *(const bf16x8*)&Bs[(n*16 + lx)*32 + ly*8];
        #pragma unroll
        for (int m = 0; m < 4; ++m)
            #pragma unroll
            for (int n = 0; n < 4; ++n)
                acc[m][n] = __builtin_amdgcn_mfma_f32_16x16x32_bf16(
                    af[m], bfv[n], acc[m][n], 0, 0, 0);
        __syncthreads();
    }

    // LN2 reduction over channels (f32 accs)
    float sP[4] = {0,0,0,0}, qP[4] = {0,0,0,0};
    #pragma unroll
    for (int n = 0; n < 4; ++n)
        #pragma unroll
        for (int m = 0; m < 4; ++m)
            #pragma unroll
            for (int r = 0; r < 4; ++r) {
                float v = acc[m][n][r];
                sP[n] += v; qP[n] += v*v;
            }
    #pragma unroll
    for (int n = 0; n < 4; ++n) {
        sP[n] += __shfl_xor(sP[n], 16); sP[n] += __shfl_xor(sP[n], 32);
        qP[n] += __shfl_xor(qP[n], 16); qP[n] += __shfl_xor(qP[n], 32);
    }
    if (ly == 0) {
        #pragma unroll
        for (int n = 0; n < 4; ++n) {
            sredS[w][n*16 + lx] = sP[n];
            sredQ[w][n*16 + lx] = qP[n];
        }
    }
    __syncthreads();
    if (t < 64) {
        float s = 0.f, q = 0.f;
        #pragma unroll
        for (int ww = 0; ww < 4; ++ww) { s += sredS[ww][t]; q += sredQ[ww][t]; }
        float m = s * (1.f/C_);
        mrM[t] = m;
        mrR[t] = rsqrtf(q*(1.f/C_) - m*m + 1e-5f);
    }
    __syncthreads();

    // residual + store f32, coalesced in 64B segments per (m,r,n)
    #pragma unroll
    for (int n = 0; n < 4; ++n) {
        int l = n*16 + lx;
        float mn = mrM[l], rs = mrR[l];
        #pragma unroll
        for (int m = 0; m < 4; ++m) {
            #pragma unroll
            for (int r = 0; r < 4; ++r) {
                int c = w*64 + m*16 + ly*4 + r;
                size_t o = ((size_t)gb*C_ + c)*NS_ + l0 + l;
                out[o] = sfeat[o] + (acc[m][n][r] - mn)*rs*gbet[c] + gbet[256 + c];
            }
        }
    }
}

// ---------------------------------------------------------------------------
extern "C" void kernel_launch(void* const* d_in, const int* in_sizes, int n_in,
                              void* d_out, int out_size, void* d_ws, size_t ws_size,
                              hipStream_t stream)
{
    (void)in_sizes; (void)n_in; (void)out_size;
    const float* search_feat   = (const float*)d_in[0];
    const float* template_feat = (const float*)d_in[2];
    const float* template_xyz  = (const float*)d_in[3];
    const float* pos_w1  = (const float*)d_in[4];
    const float* pos_b1  = (const float*)d_in[5];
    const float* pos_w2  = (const float*)d_in[6];
    const float* pos_b2  = (const float*)d_in[7];
    const float* q_w     = (const float*)d_in[8];
    const float* k_w     = (const float*)d_in[9];
    const float* v_w     = (const float*)d_in[10];
    const float* merge_w = (const float*)d_in[11];
    const float* mlp_w1  = (const float*)d_in[12];
    const float* mlp_w2  = (const float*)d_in[13];
    const float* ln1_g   = (const float*)d_in[14];
    const float* ln1_b   = (const float*)d_in[15];
    const float* ln2_g   = (const float*)d_in[16];
    const float* ln2_b   = (const float*)d_in[17];
    float* out = (float*)d_out;

    const int W_Q = 0, W_K = 65536, W_V = 131072, W_M = 196608,
              W_P = 262144, W_1 = 327680, W_2 = 589824;
    const size_t wElems = 720896;

    size_t sfE = (size_t)NS_*C_, tfE = (size_t)NT_*C_;
    int G = 8;
    while (G > 1) {
        size_t shorts = (size_t)G*(4*sfE + 2*tfE) + wElems + (size_t)G*8192;
        size_t bytes  = shorts*2 + (size_t)G*NCH*KVZ_*4 + (size_t)G*256*4 + 512;
        if (bytes <= ws_size) break;
        G >>= 1;
    }

    short* wtb  = (short*)d_ws;
    short* sfb  = wtb  + wElems;          // [G,NS,C]
    short* tfb  = sfb  + (size_t)G*sfE;   // [G,NT,C]
    short* tfpb = tfb  + (size_t)G*tfE;   // [G,NT,C]
    short* hid  = tfpb + (size_t)G*tfE;   // [G,NS,2C]; early: K | V | h
    short* mrgb = hid  + (size_t)2*G*sfE; // [G,NS,C]  LN1(merge) out
    short* KVTb = mrgb + (size_t)G*sfE;   // [G,8192]
    float* kvpf = (float*)(KVTb + (size_t)G*8192);
    float* KSfb = kvpf + (size_t)G*NCH*KVZ_;
    short* Kb = hid;
    short* Vb = hid + (size_t)G*tfE;
    short* hb = hid + (size_t)2*G*tfE;    // pos-mlp hidden h [G,NT,C]

    WPack pack;
    pack.d[0] = { q_w,     C_,  C_,  W_Q };
    pack.d[1] = { k_w,     C_,  C_,  W_K };
    pack.d[2] = { v_w,     C_,  C_,  W_V };
    pack.d[3] = { merge_w, C_,  C_,  W_M };
    pack.d[4] = { pos_w2,  C_,  C_,  W_P };
    pack.d[5] = { mlp_w1,  C2_, C2_, W_1 };
    pack.d[6] = { mlp_w2,  C2_, C_,  W_2 };
    wcast_all<<<dim3(16, 16, 7), 256, 0, stream>>>(pack, wtb);

    for (int b0 = 0; b0 < B_; b0 += G) {
        castT<<<dim3(NS_/32, C_/32, G), 256, 0, stream>>>(search_feat, sfb, NS_, b0);
        castT<<<dim3(NT_/32, C_/32, G), 256, 0, stream>>>(template_feat, tfb, NT_, b0);
        pos_h<<<dim3(NT_/16, G), 256, 0, stream>>>(template_xyz, pos_w1, pos_b1, hb, b0);
        // tfp = h @ posw2 + b2 + tf
        gemm_bf16<3,4><<<dim3(C_/128, NT_/128, G), 256, 0, stream>>>(
            hb, C_, nullptr, 0, 1<<30, wtb + W_P, pos_b2, tfb, tfpb, NT_, C_, C_);
        // K = elu(tf @ k_w)+1
        gemm_bf16<2,4><<<dim3(C_/128, NT_/128, G), 256, 0, stream>>>(
            tfb, C_, nullptr, 0, 1<<30, wtb + W_K, nullptr, nullptr, Kb, NT_, C_, C_);
        // V = tfp @ v_w
        gemm_bf16<0,4><<<dim3(C_/128, NT_/128, G), 256, 0, stream>>>(
            tfpb, C_, nullptr, 0, 1<<30, wtb + W_V, nullptr, nullptr, Vb, NT_, C_, C_);
        kv_kernel<<<dim3(H_, NCH, G), 256, 0, stream>>>(Kb, Vb, kvpf);
        kvfin<<<dim3(G), 256, 0, stream>>>(kvpf, KVTb, KSfb);
        // fused Q -> attn -> merge -> LN1
        qam_kernel<<<dim3(NS_/64, G), 256, 0, stream>>>(
            sfb, wtb + W_Q, wtb + W_M, KVTb, KSfb, ln1_g, ln1_b, mrgb);
        // hidden = relu([sf | mrg] @ mlp_w1)   (overwrites K|V|h: all dead)
        gemm_bf16<1,4><<<dim3(C2_/128, NS_/128, G), 256, 0, stream>>>(
            sfb, C_, mrgb, C_, C_, wtb + W_1, nullptr, nullptr, hid, NS_, C2_, C2_);
        // fused mlp2 + LN2 + residual + transpose
        m2f_kernel<<<dim3(NS_/64, G), 256, 0, stream>>>(
            hid, wtb + W_2, search_feat, ln2_g, ln2_b, out, b0);
    }
}

// Round 5
// 537.795 us; speedup vs baseline: 1.3718x; 1.1184x over previous
//
#include <hip/hip_runtime.h>
#include <math.h>

#define B_  8
#define C_  256
#define NS_ 16384
#define NT_ 8192
#define H_  8
#define D_  32
#define C2_ 512
#define NCH 4
#define KVZ_ (H_*D_*D_ + H_*D_)   // 8448 floats per (batch, chunk)

typedef __attribute__((ext_vector_type(8))) short bf16x8;
typedef __attribute__((ext_vector_type(4))) short bf16x4;
typedef __attribute__((ext_vector_type(4))) float f32x4;

__device__ __forceinline__ short f2bf(float f) {
    unsigned u = __float_as_uint(f);
    u = (u + 0x7fffu + ((u >> 16) & 1u)) >> 16;
    return (short)u;
}
__device__ __forceinline__ float bf2f(short s) {
    return __uint_as_float(((unsigned)(unsigned short)s) << 16);
}
__device__ __forceinline__ float2 bfpair(unsigned u) {
    float2 r;
    r.x = __uint_as_float(u << 16);
    r.y = __uint_as_float(u & 0xffff0000u);
    return r;
}
__device__ __forceinline__ void load_lds16(const void* g, void* l) {
    __builtin_amdgcn_global_load_lds(
        (const __attribute__((address_space(1))) unsigned int*)g,
        (__attribute__((address_space(3))) unsigned int*)l, 16, 0, 0);
}

// ---------------------------------------------------------------------------
// transpose-cast: in [B, C, NLEN] f32 -> ob [G, NLEN, C] bf16
__global__ __launch_bounds__(256)
void castT(const float* __restrict__ in, short* __restrict__ ob, int NLEN, int b0)
{
    __shared__ float tl[32][33];
    int g = blockIdx.z, gb = b0 + g;
    int n0 = blockIdx.x * 32, c0 = blockIdx.y * 32;
    int t = threadIdx.x, tr = t >> 5, tc = t & 31;
    #pragma unroll
    for (int i = 0; i < 4; ++i)
        tl[tr + 8*i][tc] = in[((size_t)gb*C_ + c0 + tr + 8*i)*NLEN + n0 + tc];
    __syncthreads();
    #pragma unroll
    for (int i = 0; i < 4; ++i)
        ob[((size_t)g*NLEN + n0 + tr + 8*i)*C_ + c0 + tc] = f2bf(tl[tc][tr + 8*i]);
}

// ---------------------------------------------------------------------------
// weight transpose-cast: w [K,N] f32 -> wt[off + n*ldo + k] bf16
struct WDesc { const float* src; int K; int N; int off; int ldo; };
struct WPack { WDesc d[7]; };

__global__ __launch_bounds__(256)
void wcast_all(WPack p, short* __restrict__ wt)
{
    __shared__ float tl[32][33];
    WDesc d = p.d[blockIdx.z];
    int kt = blockIdx.x * 32, nt = blockIdx.y * 32;
    if (kt >= d.K || nt >= d.N) return;
    int t = threadIdx.x, tr = t >> 5, tc = t & 31;
    #pragma unroll
    for (int i = 0; i < 4; ++i)
        tl[tr + 8*i][tc] = d.src[(size_t)(kt + tr + 8*i)*d.N + nt + tc];
    __syncthreads();
    short* o = wt + d.off;
    #pragma unroll
    for (int i = 0; i < 4; ++i)
        o[(size_t)(nt + tr + 8*i)*d.ldo + kt + tc] = f2bf(tl[tc][tr + 8*i]);
}

// ---------------------------------------------------------------------------
// fused V-weight: Wv2[n, 256+k] = W_pv^T[n,k] = sum_m v_w[m,n]*posw2[k,m]
// and bv[n] = sum_j b2[j]*v_w[j,n].  grid(256), 256 threads.
__global__ __launch_bounds__(256)
void fusew(short* __restrict__ wv2, const short* __restrict__ wp,
           const float* __restrict__ b2, const float* __restrict__ v_w,
           float* __restrict__ bv)
{
    int n = blockIdx.x, k = threadIdx.x;
    __shared__ float vrow[256];
    __shared__ float bred[256];
    vrow[k] = bf2f(wv2[(size_t)n*512 + k]);
    bred[k] = b2[k] * v_w[(size_t)k*C_ + n];
    __syncthreads();
    float s = 0.f;
    for (int m = 0; m < 256; ++m)
        s += vrow[m] * bf2f(wp[m*256 + k]);   // wp[m*256+k] = posw2[k, m]
    wv2[(size_t)n*512 + 256 + k] = f2bf(s);
    for (int off2 = 128; off2 > 0; off2 >>= 1) {
        __syncthreads();
        if (k < off2) bred[k] += bred[k + off2];
    }
    if (k == 0) bv[n] = bred[0];
}

// ---------------------------------------------------------------------------
// h = relu(xyz @ w1 + b1) -> bf16 [G, NT, C]
__global__ __launch_bounds__(256)
void pos_h(const float* __restrict__ xyz, const float* __restrict__ w1,
           const float* __restrict__ b1, short* __restrict__ hb, int b0)
{
    int g = blockIdx.y, gb = b0 + g;
    int r0 = blockIdx.x * 16;
    int t = threadIdx.x;
    float w1x = w1[t], w1y = w1[C_ + t], w1z = w1[2*C_ + t], bb = b1[t];
    for (int r = 0; r < 16; ++r) {
        const float* p = xyz + ((size_t)gb*NT_ + r0 + r)*3;
        float h = fmaxf(p[0]*w1x + p[1]*w1y + p[2]*w1z + bb, 0.f);
        hb[((size_t)g*NT_ + r0 + r)*C_ + t] = f2bf(h);
    }
}

// ---------------------------------------------------------------------------
// bf16 MFMA GEMM, 128 x (NF*32) tile, BK=32, 4 waves (2x2), 4 x NF fragments.
// XCD-grouped tile remap: the nbs column-blocks of one A-panel run
// consecutively on the SAME XCD so A hits that XCD's L2.
// A concat: k < split -> A0 (lda0), else A1 (lda1).
// EPI 0: none, 1: relu, 2: elu+1, 3: +bias+addmat, 4: +bias
template<int EPI, int NF>
__global__ __launch_bounds__(256)
void gemm_bf16(const short* __restrict__ A0, int lda0,
               const short* __restrict__ A1, int lda1, int split,
               const short* __restrict__ Wt,
               const float* __restrict__ bias,
               const short* __restrict__ addmat,
               short* __restrict__ outp,
               int M, int N, int K)
{
    __shared__ __align__(16) short As[128*32];
    __shared__ __align__(16) short Bs[NF*32*32];
    int g = blockIdx.z;
    int nbs = gridDim.x, Mb = gridDim.y;
    int nb, mb;
    if ((Mb & 7) == 0) {
        int lin = blockIdx.y * nbs + blockIdx.x;
        int xcd = lin & 7, j = lin >> 3;
        nb = (j % nbs) * (NF*32);
        mb = ((j / nbs) * 8 + xcd) * 128;
    } else {
        nb = blockIdx.x * (NF*32);
        mb = blockIdx.y * 128;
    }
    int t = threadIdx.x;
    int lane = t & 63;
    int w = t >> 6, wr = w >> 1, wc = w & 1;

    const short* A0g = A0 + (size_t)g*M*lda0;
    const short* A1g = A1 ? (A1 + (size_t)g*M*lda1) : A0;

    f32x4 acc[4][NF] = {};

    int r4 = t >> 2;
    int ch = t & 3;

    for (int kb = 0; kb < K; kb += 32) {
        const short* Ab; int lda, kc;
        if (kb < split) { Ab = A0g; lda = lda0; kc = kb; }
        else            { Ab = A1g; lda = lda1; kc = kb - split; }
        const short* as0 = Ab + (size_t)(mb + r4)*lda + kc + ch*8;
        load_lds16(as0,                   &As[r4*32 + ch*8]);
        load_lds16(as0 + (size_t)64*lda,  &As[(r4 + 64)*32 + ch*8]);
        #pragma unroll
        for (int i = 0; i < NF/2; ++i) {
            int row = r4 + 64*i;
            load_lds16(Wt + (size_t)(nb + row)*K + kb + ch*8, &Bs[row*32 + ch*8]);
        }
        __syncthreads();

        int kq = (lane >> 4) * 8;
        bf16x8 af[4], bfr[NF];
        #pragma unroll
        for (int m = 0; m < 4; ++m)
            af[m] = *(const bf16x8*)&As[(wr*64 + m*16 + (lane & 15))*32 + kq];
        #pragma unroll
        for (int n = 0; n < NF; ++n)
            bfr[n] = *(const bf16x8*)&Bs[(wc*(NF*16) + n*16 + (lane & 15))*32 + kq];
        #pragma unroll
        for (int m = 0; m < 4; ++m)
            #pragma unroll
            for (int n = 0; n < NF; ++n)
                acc[m][n] = __builtin_amdgcn_mfma_f32_16x16x32_bf16(
                    af[m], bfr[n], acc[m][n], 0, 0, 0);
        __syncthreads();
    }

    short* og = outp + (size_t)g*M*N;
    const short* am = (EPI == 3) ? (addmat + (size_t)g*M*N) : nullptr;
    int rq = (lane >> 4) * 4;
    int cl = lane & 15;
    #pragma unroll
    for (int m = 0; m < 4; ++m) {
        #pragma unroll
        for (int r = 0; r < 4; ++r) {
            int row = mb + wr*64 + m*16 + rq + r;
            size_t ro = (size_t)row * N;
            #pragma unroll
            for (int n = 0; n < NF; ++n) {
                int col = nb + wc*(NF*16) + n*16 + cl;
                float v = acc[m][n][r];
                if constexpr (EPI == 1) v = fmaxf(v, 0.f);
                if constexpr (EPI == 2) v = (v > 0.f) ? (v + 1.f) : __expf(v);
                if constexpr (EPI == 3) v = v + bias[col] + bf2f(am[ro + col]);
                if constexpr (EPI == 4) v = v + bias[col];
                og[ro + col] = f2bf(v);
            }
        }
    }
}

// ---------------------------------------------------------------------------
// KV[h,d,vd] partial sums over NT/NCH rows; Ksum[h,d] likewise. grid (H,NCH,G)
__global__ __launch_bounds__(256)
void kv_kernel(const short* __restrict__ Kb, const short* __restrict__ Vb,
               float* __restrict__ kvz)
{
    __shared__ float SK[32][D_];
    __shared__ float SV[32][D_];
    int h = blockIdx.x, chk = blockIdx.y, g = blockIdx.z;
    int t = threadIdx.x;
    int d = t >> 3, v0 = (t & 7) * 4;
    int lr = t >> 3, lc = (t & 7) * 4;
    float acc[4] = {0.f, 0.f, 0.f, 0.f};
    float ksum = 0.f;
    int s0beg = chk * (NT_/NCH), s0end = s0beg + NT_/NCH;
    for (int s0 = s0beg; s0 < s0end; s0 += 32) {
        size_t off = ((size_t)g*NT_ + s0 + lr)*C_ + h*D_ + lc;
        uint2 ku = *(const uint2*)(Kb + off);
        uint2 vu = *(const uint2*)(Vb + off);
        float2 k0 = bfpair(ku.x), k1 = bfpair(ku.y);
        float2 w0 = bfpair(vu.x), w1 = bfpair(vu.y);
        SK[lr][lc] = k0.x; SK[lr][lc+1] = k0.y; SK[lr][lc+2] = k1.x; SK[lr][lc+3] = k1.y;
        SV[lr][lc] = w0.x; SV[lr][lc+1] = w0.y; SV[lr][lc+2] = w1.x; SV[lr][lc+3] = w1.y;
        __syncthreads();
        #pragma unroll
        for (int ss = 0; ss < 32; ++ss) {
            float kd = SK[ss][d];
            #pragma unroll
            for (int j = 0; j < 4; ++j) acc[j] += kd * SV[ss][v0 + j];
            ksum += kd;
        }
        __syncthreads();
    }
    float* KV = kvz + ((size_t)g*NCH + chk)*KVZ_;
    #pragma unroll
    for (int j = 0; j < 4; ++j) KV[h*D_*D_ + d*D_ + v0 + j] = acc[j];
    if ((t & 7) == 0) KV[H_*D_*D_ + h*D_ + d] = ksum;
}

// ---------------------------------------------------------------------------
// reduce NCH partials -> KVT bf16 [G][h][v][d]  +  KSf f32 [G][h][d]. grid (G)
__global__ __launch_bounds__(256)
void kvfin(const float* __restrict__ kvp, short* __restrict__ KVT,
           float* __restrict__ KSf)
{
    int g = blockIdx.x, t = threadIdx.x;
    const float* p = kvp + (size_t)g*NCH*KVZ_;
    for (int idx = t; idx < H_*D_*D_; idx += 256) {
        int h = idx >> 10, rem = idx & 1023, v = rem >> 5, d = rem & 31;
        float s = 0.f;
        #pragma unroll
        for (int c = 0; c < NCH; ++c) s += p[c*KVZ_ + h*1024 + d*32 + v];
        KVT[(size_t)g*8192 + h*1024 + v*32 + d] = f2bf(s);
    }
    {
        float s = 0.f;
        #pragma unroll
        for (int c = 0; c < NCH; ++c) s += p[c*KVZ_ + H_*D_*D_ + t];
        KSf[(size_t)g*256 + t] = s;
    }
}

// ---------------------------------------------------------------------------
// Fused: Q = elu(sf@q_w)+1 ; msg = (Q (x)_h KV) * Z ; mrg = LN1(msg @ merge_w)
// All products computed TRANSPOSED (C rows = channels, cols = sequence l).
__global__ __launch_bounds__(256)
void qam_kernel(const short* __restrict__ sfb, const short* __restrict__ wtq,
                const short* __restrict__ wtm, const short* __restrict__ KVT,
                const float* __restrict__ KSf,
                const float* __restrict__ ln1g, const float* __restrict__ ln1b,
                short* __restrict__ mrg)
{
    __shared__ short QT[64][264];                 // Q, then msg, then LN1 out
    __shared__ __align__(16) short As[64*32];     // sf staging
    __shared__ __align__(16) short Bs[256*32];    // weight staging
    __shared__ float sredS[4][64], sredQ[4][64];
    __shared__ float mrM[64], mrR[64];
    __shared__ float gbet[512];

    int g = blockIdx.y;
    int l0 = blockIdx.x * 64;
    int t = threadIdx.x;
    int lane = t & 63, w = t >> 6;
    int lx = lane & 15, ly = lane >> 4;

    gbet[t]       = ln1g[t];
    gbet[256 + t] = ln1b[t];

    const short* sfg = sfb + ((size_t)g*NS_ + l0)*C_;

    // ---- phase 1: Q^T = Wq^T(A) @ sf^T(B), K=256
    f32x4 acc[4][4] = {};
    for (int kb = 0; kb < C_; kb += 32) {
        load_lds16(sfg + (size_t)(t>>2)*C_ + kb + (t&3)*8, &As[(t>>2)*32 + (t&3)*8]);
        #pragma unroll
        for (int i = 0; i < 4; ++i) {
            int row = (t>>2) + 64*i;
            load_lds16(wtq + (size_t)row*C_ + kb + (t&3)*8, &Bs[row*32 + (t&3)*8]);
        }
        __syncthreads();
        bf16x8 af[4], bfv[4];
        #pragma unroll
        for (int m = 0; m < 4; ++m)
            af[m] = *(const bf16x8*)&Bs[(w*64 + m*16 + lx)*32 + ly*8];
        #pragma unroll
        for (int n = 0; n < 4; ++n)
            bfv[n] = *(const bf16x8*)&As[(n*16 + lx)*32 + ly*8];
        #pragma unroll
        for (int m = 0; m < 4; ++m)
            #pragma unroll
            for (int n = 0; n < 4; ++n)
                acc[m][n] = __builtin_amdgcn_mfma_f32_16x16x32_bf16(
                    af[m], bfv[n], acc[m][n], 0, 0, 0);
        __syncthreads();
    }
    #pragma unroll
    for (int m = 0; m < 4; ++m) {
        int c0 = w*64 + m*16 + ly*4;
        #pragma unroll
        for (int n = 0; n < 4; ++n) {
            bf16x4 pk;
            #pragma unroll
            for (int r = 0; r < 4; ++r) {
                float v = acc[m][n][r];
                pk[r] = f2bf((v > 0.f) ? (v + 1.f) : __expf(v));
            }
            *(bf16x4*)&QT[n*16 + lx][c0] = pk;
        }
    }
    __syncthreads();

    // ---- phase 2: msg^T = KV^T(A) @ Q^T(B), K=32 per head; Z via dot+shfl
    const short* kvg = KVT + (size_t)g*8192;
    bf16x8 bq[2][4];
    #pragma unroll
    for (int hh = 0; hh < 2; ++hh)
        #pragma unroll
        for (int n = 0; n < 4; ++n)
            bq[hh][n] = *(const bf16x8*)&QT[n*16 + lx][(2*w + hh)*32 + ly*8];
    float z[2][4];
    #pragma unroll
    for (int hh = 0; hh < 2; ++hh) {
        const float* kp = KSf + (size_t)g*256 + (2*w + hh)*32 + ly*8;
        float4 ka = *(const float4*)kp;
        float4 kb4 = *(const float4*)(kp + 4);
        float kr[8] = {ka.x, ka.y, ka.z, ka.w, kb4.x, kb4.y, kb4.z, kb4.w};
        #pragma unroll
        for (int n = 0; n < 4; ++n) {
            float s = 0.f;
            #pragma unroll
            for (int j = 0; j < 8; ++j) s += bf2f(bq[hh][n][j]) * kr[j];
            s += __shfl_xor(s, 16);
            s += __shfl_xor(s, 32);
            z[hh][n] = 1.f / (s + 1e-6f);
        }
    }
    f32x4 zero = {0.f, 0.f, 0.f, 0.f};
    f32x4 a2[4][4];
    #pragma unroll
    for (int m = 0; m < 4; ++m) {
        int h = 2*w + (m >> 1);
        bf16x8 afk = *(const bf16x8*)(kvg + ((size_t)h*1024 + ((m&1)*16 + lx)*32 + ly*8));
        #pragma unroll
        for (int n = 0; n < 4; ++n)
            a2[m][n] = __builtin_amdgcn_mfma_f32_16x16x32_bf16(
                afk, bq[m>>1][n], zero, 0, 0, 0);
    }
    #pragma unroll
    for (int m = 0; m < 4; ++m) {
        int c0 = w*64 + m*16 + ly*4;
        #pragma unroll
        for (int n = 0; n < 4; ++n) {
            bf16x4 pk;
            #pragma unroll
            for (int r = 0; r < 4; ++r)
                pk[r] = f2bf(a2[m][n][r] * z[m>>1][n]);
            *(bf16x4*)&QT[n*16 + lx][c0] = pk;
        }
    }
    __syncthreads();

    // ---- phase 3: mrg^T = Wm^T(A) @ msg^T(B), K=256
    f32x4 acc3[4][4] = {};
    for (int kb = 0; kb < C_; kb += 32) {
        #pragma unroll
        for (int i = 0; i < 4; ++i) {
            int row = (t>>2) + 64*i;
            load_lds16(wtm + (size_t)row*C_ + kb + (t&3)*8, &Bs[row*32 + (t&3)*8]);
        }
        __syncthreads();
        bf16x8 af[4], bfv[4];
        #pragma unroll
        for (int m = 0; m < 4; ++m)
            af[m] = *(const bf16x8*)&Bs[(w*64 + m*16 + lx)*32 + ly*8];
        #pragma unroll
        for (int n = 0; n < 4; ++n)
            bfv[n] = *(const bf16x8*)&QT[n*16 + lx][kb + ly*8];
        #pragma unroll
        for (int m = 0; m < 4; ++m)
            #pragma unroll
            for (int n = 0; n < 4; ++n)
                acc3[m][n] = __builtin_amdgcn_mfma_f32_16x16x32_bf16(
                    af[m], bfv[n], acc3[m][n], 0, 0, 0);
        __syncthreads();
    }

    // ---- LN1 over channels (f32 accs)
    float sP[4] = {0,0,0,0}, qP[4] = {0,0,0,0};
    #pragma unroll
    for (int n = 0; n < 4; ++n)
        #pragma unroll
        for (int m = 0; m < 4; ++m)
            #pragma unroll
            for (int r = 0; r < 4; ++r) {
                float v = acc3[m][n][r];
                sP[n] += v; qP[n] += v*v;
            }
    #pragma unroll
    for (int n = 0; n < 4; ++n) {
        sP[n] += __shfl_xor(sP[n], 16); sP[n] += __shfl_xor(sP[n], 32);
        qP[n] += __shfl_xor(qP[n], 16); qP[n] += __shfl_xor(qP[n], 32);
    }
    if (ly == 0) {
        #pragma unroll
        for (int n = 0; n < 4; ++n) {
            sredS[w][n*16 + lx] = sP[n];
            sredQ[w][n*16 + lx] = qP[n];
        }
    }
    __syncthreads();
    if (t < 64) {
        float s = 0.f, q = 0.f;
        #pragma unroll
        for (int ww = 0; ww < 4; ++ww) { s += sredS[ww][t]; q += sredQ[ww][t]; }
        float m = s * (1.f/C_);
        mrM[t] = m;
        mrR[t] = rsqrtf(q*(1.f/C_) - m*m + 1e-5f);
    }
    __syncthreads();
    #pragma unroll
    for (int n = 0; n < 4; ++n) {
        float mn = mrM[n*16 + lx], rs = mrR[n*16 + lx];
        #pragma unroll
        for (int m = 0; m < 4; ++m) {
            int c0 = w*64 + m*16 + ly*4;
            bf16x4 pk;
            #pragma unroll
            for (int r = 0; r < 4; ++r) {
                int c = c0 + r;
                pk[r] = f2bf((acc3[m][n][r] - mn)*rs*gbet[c] + gbet[256 + c]);
            }
            *(bf16x4*)&QT[n*16 + lx][c0] = pk;
        }
    }
    __syncthreads();
    short* og = mrg + ((size_t)g*NS_ + l0)*C_;
    int row = t >> 2;
    #pragma unroll
    for (int i = 0; i < 8; ++i) {
        int chk = (t & 3) + 4*i;
        *(uint4*)(og + (size_t)row*C_ + chk*8) = *(const uint4*)&QT[row][chk*8];
    }
}

// ---------------------------------------------------------------------------
// Fused mlp2 + LN2 + residual + transpose, occupancy-targeted:
// m2^T = W2t(A: 256 out-ch rows, K=512) @ hidden^T(B). LN2 via cross-wave
// reduce; normalized bf16 staged in LDS (stride 258 = conflict-free column
// reads); coalesced f32 residual+store. grid (NS/64, G), 4 waves.
__global__ __launch_bounds__(256, 4)
void m2f_kernel(const short* __restrict__ hid, const short* __restrict__ wt2,
                const float* __restrict__ sfeat,
                const float* __restrict__ ln2g, const float* __restrict__ ln2b,
                float* __restrict__ out, int b0)
{
    __shared__ __align__(16) short sh[64*258];  // As(8192)|Bs(2048), later QTm
    __shared__ float sredS[4][64], sredQ[4][64];
    __shared__ float mrM[64], mrR[64];
    __shared__ float gbet[512];

    int g = blockIdx.y, gb = b0 + g;
    int l0 = blockIdx.x * 64;
    int t = threadIdx.x;
    int lane = t & 63, w = t >> 6;
    int lx = lane & 15, ly = lane >> 4;

    gbet[t]       = ln2g[t];
    gbet[256 + t] = ln2b[t];

    short* As = sh;
    short* Bs = sh + 8192;

    const short* hg = hid + ((size_t)g*NS_ + l0)*C2_;
    f32x4 acc[4][4] = {};
    for (int kb = 0; kb < C2_; kb += 32) {
        #pragma unroll
        for (int i = 0; i < 4; ++i) {
            int row = (t>>2) + 64*i;
            load_lds16(wt2 + (size_t)row*C2_ + kb + (t&3)*8, &As[row*32 + (t&3)*8]);
        }
        load_lds16(hg + (size_t)(t>>2)*C2_ + kb + (t&3)*8, &Bs[(t>>2)*32 + (t&3)*8]);
        __syncthreads();
        bf16x8 af[4], bfv[4];
        #pragma unroll
        for (int m = 0; m < 4; ++m)
            af[m] = *(const bf16x8*)&As[(w*64 + m*16 + lx)*32 + ly*8];
        #pragma unroll
        for (int n = 0; n < 4; ++n)
            bfv[n] = *(const bf16x8*)&Bs[(n*16 + lx)*32 + ly*8];
        #pragma unroll
        for (int m = 0; m < 4; ++m)
            #pragma unroll
            for (int n = 0; n < 4; ++n)
                acc[m][n] = __builtin_amdgcn_mfma_f32_16x16x32_bf16(
                    af[m], bfv[n], acc[m][n], 0, 0, 0);
        __syncthreads();
    }

    // LN2 reduction over channels (f32 accs)
    float sP[4] = {0,0,0,0}, qP[4] = {0,0,0,0};
    #pragma unroll
    for (int n = 0; n < 4; ++n)
        #pragma unroll
        for (int m = 0; m < 4; ++m)
            #pragma unroll
            for (int r = 0; r < 4; ++r) {
                float v = acc[m][n][r];
                sP[n] += v; qP[n] += v*v;
            }
    #pragma unroll
    for (int n = 0; n < 4; ++n) {
        sP[n] += __shfl_xor(sP[n], 16); sP[n] += __shfl_xor(sP[n], 32);
        qP[n] += __shfl_xor(qP[n], 16); qP[n] += __shfl_xor(qP[n], 32);
    }
    if (ly == 0) {
        #pragma unroll
        for (int n = 0; n < 4; ++n) {
            sredS[w][n*16 + lx] = sP[n];
            sredQ[w][n*16 + lx] = qP[n];
        }
    }
    __syncthreads();
    if (t < 64) {
        float s = 0.f, q = 0.f;
        #pragma unroll
        for (int ww = 0; ww < 4; ++ww) { s += sredS[ww][t]; q += sredQ[ww][t]; }
        float m = s * (1.f/C_);
        mrM[t] = m;
        mrR[t] = rsqrtf(q*(1.f/C_) - m*m + 1e-5f);
    }
    __syncthreads();

    // pack normalized bf16 into QTm (overlays As/Bs; both dead)
    #pragma unroll
    for (int n = 0; n < 4; ++n) {
        int l = n*16 + lx;
        float mn = mrM[l], rs = mrR[l];
        #pragma unroll
        for (int m = 0; m < 4; ++m) {
            int c0 = w*64 + m*16 + ly*4;
            #pragma unroll
            for (int r = 0; r < 4; ++r)
                sh[l*258 + c0 + r] =
                    f2bf((acc[m][n][r] - mn)*rs*gbet[c0+r] + gbet[256 + c0 + r]);
        }
    }
    __syncthreads();

    // coalesced residual + f32 store: lanes sweep l (contiguous 256B/wave)
    int l = t & 63, cg = t >> 6;
    const float* sfp = sfeat + (size_t)gb*C_*NS_ + l0;
    float* op = out + (size_t)gb*C_*NS_ + l0;
    for (int ci = 0; ci < 64; ++ci) {
        int c = cg*64 + ci;
        size_t o = (size_t)c*NS_ + l;
        op[o] = sfp[o] + bf2f(sh[l*258 + c]);
    }
}

// ---------------------------------------------------------------------------
extern "C" void kernel_launch(void* const* d_in, const int* in_sizes, int n_in,
                              void* d_out, int out_size, void* d_ws, size_t ws_size,
                              hipStream_t stream)
{
    (void)in_sizes; (void)n_in; (void)out_size;
    const float* search_feat   = (const float*)d_in[0];
    const float* template_feat = (const float*)d_in[2];
    const float* template_xyz  = (const float*)d_in[3];
    const float* pos_w1  = (const float*)d_in[4];
    const float* pos_b1  = (const float*)d_in[5];
    const float* pos_w2  = (const float*)d_in[6];
    const float* pos_b2  = (const float*)d_in[7];
    const float* q_w     = (const float*)d_in[8];
    const float* k_w     = (const float*)d_in[9];
    const float* v_w     = (const float*)d_in[10];
    const float* merge_w = (const float*)d_in[11];
    const float* mlp_w1  = (const float*)d_in[12];
    const float* mlp_w2  = (const float*)d_in[13];
    const float* ln1_g   = (const float*)d_in[14];
    const float* ln1_b   = (const float*)d_in[15];
    const float* ln2_g   = (const float*)d_in[16];
    const float* ln2_b   = (const float*)d_in[17];
    float* out = (float*)d_out;

    // packed bf16 weights: q,k,merge,posw2 (256x256), mlp1 (512x512),
    // mlp2 (256x512), fused V [v_w | posw2@v_w] (256x512)
    const int W_Q = 0, W_K = 65536, W_M = 131072, W_P = 196608,
              W_1 = 262144, W_2 = 524288, W_V2 = 655360;
    const size_t wElems = 786432;

    size_t sfE = (size_t)NS_*C_, tfE = (size_t)NT_*C_;
    int G = 8;
    while (G > 1) {
        size_t shorts = (size_t)G*(4*sfE + tfE + 8192) + wElems;
        size_t bytes  = shorts*2 + (size_t)G*(NCH*KVZ_ + 256)*4 + 256*4 + 1024;
        if (bytes <= ws_size) break;
        G >>= 1;
    }

    short* wtb  = (short*)d_ws;
    short* sfb  = wtb  + wElems;          // [G,NS,C]
    short* tfb  = sfb  + (size_t)G*sfE;   // [G,NT,C]
    short* hid  = tfb  + (size_t)G*tfE;   // [G,NS,2C]; early: K | V | h
    short* mrgb = hid  + (size_t)2*G*sfE; // [G,NS,C]  LN1(merge) out
    short* KVTb = mrgb + (size_t)G*sfE;   // [G,8192]
    float* kvpf = (float*)(KVTb + (size_t)G*8192);
    float* KSfb = kvpf + (size_t)G*NCH*KVZ_;
    float* bvf  = KSfb + (size_t)G*256;
    short* Kb = hid;
    short* Vb = hid + (size_t)G*tfE;
    short* hb = hid + (size_t)2*G*tfE;    // pos-mlp hidden h [G,NT,C]

    WPack pack;
    pack.d[0] = { q_w,     C_,  C_,  W_Q,  C_  };
    pack.d[1] = { k_w,     C_,  C_,  W_K,  C_  };
    pack.d[2] = { merge_w, C_,  C_,  W_M,  C_  };
    pack.d[3] = { pos_w2,  C_,  C_,  W_P,  C_  };
    pack.d[4] = { mlp_w1,  C2_, C2_, W_1,  C2_ };
    pack.d[5] = { mlp_w2,  C2_, C_,  W_2,  C2_ };
    pack.d[6] = { v_w,     C_,  C_,  W_V2, C2_ };  // first half of fused V
    wcast_all<<<dim3(16, 16, 7), 256, 0, stream>>>(pack, wtb);
    fusew<<<dim3(256), 256, 0, stream>>>(wtb + W_V2, wtb + W_P, pos_b2, v_w, bvf);

    for (int b0 = 0; b0 < B_; b0 += G) {
        castT<<<dim3(NS_/32, C_/32, G), 256, 0, stream>>>(search_feat, sfb, NS_, b0);
        castT<<<dim3(NT_/32, C_/32, G), 256, 0, stream>>>(template_feat, tfb, NT_, b0);
        pos_h<<<dim3(NT_/16, G), 256, 0, stream>>>(template_xyz, pos_w1, pos_b1, hb, b0);
        // K = elu(tf @ k_w)+1
        gemm_bf16<2,4><<<dim3(C_/128, NT_/128, G), 256, 0, stream>>>(
            tfb, C_, nullptr, 0, 1<<30, wtb + W_K, nullptr, nullptr, Kb, NT_, C_, C_);
        // V = [tf | h] @ [v_w ; posw2@v_w] + (b2@v_w)
        gemm_bf16<4,4><<<dim3(C_/128, NT_/128, G), 256, 0, stream>>>(
            tfb, C_, hb, C_, C_, wtb + W_V2, bvf, nullptr, Vb, NT_, C_, C2_);
        kv_kernel<<<dim3(H_, NCH, G), 256, 0, stream>>>(Kb, Vb, kvpf);
        kvfin<<<dim3(G), 256, 0, stream>>>(kvpf, KVTb, KSfb);
        // fused Q -> attn -> merge -> LN1
        qam_kernel<<<dim3(NS_/64, G), 256, 0, stream>>>(
            sfb, wtb + W_Q, wtb + W_M, KVTb, KSfb, ln1_g, ln1_b, mrgb);
        // hidden = relu([sf | mrg] @ mlp_w1)   (overwrites K|V|h: all dead)
        gemm_bf16<1,4><<<dim3(C2_/128, NS_/128, G), 256, 0, stream>>>(
            sfb, C_, mrgb, C_, C_, wtb + W_1, nullptr, nullptr, hid, NS_, C2_, C2_);
        // fused mlp2 + LN2 + residual + transpose
        m2f_kernel<<<dim3(NS_/64, G), 256, 0, stream>>>(
            hid, wtb + W_2, search_feat, ln2_g, ln2_b, out, b0);
    }
}

// Round 6
// 526.730 us; speedup vs baseline: 1.4006x; 1.0210x over previous
//
#include <hip/hip_runtime.h>
#include <math.h>

#define B_  8
#define C_  256
#define NS_ 16384
#define NT_ 8192
#define H_  8
#define D_  32
#define C2_ 512
#define NCH 4
#define KVZ_ (H_*D_*D_ + H_*D_)   // 8448 floats per (batch, chunk)

typedef __attribute__((ext_vector_type(8))) short bf16x8;
typedef __attribute__((ext_vector_type(4))) short bf16x4;
typedef __attribute__((ext_vector_type(4))) float f32x4;

__device__ __forceinline__ short f2bf(float f) {
    unsigned u = __float_as_uint(f);
    u = (u + 0x7fffu + ((u >> 16) & 1u)) >> 16;
    return (short)u;
}
__device__ __forceinline__ float bf2f(short s) {
    return __uint_as_float(((unsigned)(unsigned short)s) << 16);
}
__device__ __forceinline__ float2 bfpair(unsigned u) {
    float2 r;
    r.x = __uint_as_float(u << 16);
    r.y = __uint_as_float(u & 0xffff0000u);
    return r;
}
__device__ __forceinline__ void load_lds16(const void* g, void* l) {
    __builtin_amdgcn_global_load_lds(
        (const __attribute__((address_space(1))) unsigned int*)g,
        (__attribute__((address_space(3))) unsigned int*)l, 16, 0, 0);
}

// ---------------------------------------------------------------------------
// transpose-cast: in [B, C, NLEN] f32 -> ob [G, NLEN, C] bf16
__global__ __launch_bounds__(256)
void castT(const float* __restrict__ in, short* __restrict__ ob, int NLEN, int b0)
{
    __shared__ float tl[32][33];
    int g = blockIdx.z, gb = b0 + g;
    int n0 = blockIdx.x * 32, c0 = blockIdx.y * 32;
    int t = threadIdx.x, tr = t >> 5, tc = t & 31;
    #pragma unroll
    for (int i = 0; i < 4; ++i)
        tl[tr + 8*i][tc] = in[((size_t)gb*C_ + c0 + tr + 8*i)*NLEN + n0 + tc];
    __syncthreads();
    #pragma unroll
    for (int i = 0; i < 4; ++i)
        ob[((size_t)g*NLEN + n0 + tr + 8*i)*C_ + c0 + tc] = f2bf(tl[tc][tr + 8*i]);
}

// ---------------------------------------------------------------------------
// weight transpose-cast: w [K,N] f32 -> wt[off + n*ldo + k] bf16
struct WDesc { const float* src; int K; int N; int off; int ldo; };
struct WPack { WDesc d[7]; };

__global__ __launch_bounds__(256)
void wcast_all(WPack p, short* __restrict__ wt)
{
    __shared__ float tl[32][33];
    WDesc d = p.d[blockIdx.z];
    int kt = blockIdx.x * 32, nt = blockIdx.y * 32;
    if (kt >= d.K || nt >= d.N) return;
    int t = threadIdx.x, tr = t >> 5, tc = t & 31;
    #pragma unroll
    for (int i = 0; i < 4; ++i)
        tl[tr + 8*i][tc] = d.src[(size_t)(kt + tr + 8*i)*d.N + nt + tc];
    __syncthreads();
    short* o = wt + d.off;
    #pragma unroll
    for (int i = 0; i < 4; ++i)
        o[(size_t)(nt + tr + 8*i)*d.ldo + kt + tc] = f2bf(tl[tc][tr + 8*i]);
}

// ---------------------------------------------------------------------------
// fused V-weight: Wv2[n, 256+k] = sum_m v_w[m,n]*posw2[k,m];  bv[n] = b2 @ v_w
__global__ __launch_bounds__(256)
void fusew(short* __restrict__ wv2, const short* __restrict__ wp,
           const float* __restrict__ b2, const float* __restrict__ v_w,
           float* __restrict__ bv)
{
    int n = blockIdx.x, k = threadIdx.x;
    __shared__ float vrow[256];
    __shared__ float bred[256];
    vrow[k] = bf2f(wv2[(size_t)n*512 + k]);
    bred[k] = b2[k] * v_w[(size_t)k*C_ + n];
    __syncthreads();
    float s = 0.f;
    for (int m = 0; m < 256; ++m)
        s += vrow[m] * bf2f(wp[m*256 + k]);
    wv2[(size_t)n*512 + 256 + k] = f2bf(s);
    for (int off2 = 128; off2 > 0; off2 >>= 1) {
        __syncthreads();
        if (k < off2) bred[k] += bred[k + off2];
    }
    if (k == 0) bv[n] = bred[0];
}

// ---------------------------------------------------------------------------
// h = relu(xyz @ w1 + b1) -> bf16 [G, NT, C]
__global__ __launch_bounds__(256)
void pos_h(const float* __restrict__ xyz, const float* __restrict__ w1,
           const float* __restrict__ b1, short* __restrict__ hb, int b0)
{
    int g = blockIdx.y, gb = b0 + g;
    int r0 = blockIdx.x * 16;
    int t = threadIdx.x;
    float w1x = w1[t], w1y = w1[C_ + t], w1z = w1[2*C_ + t], bb = b1[t];
    for (int r = 0; r < 16; ++r) {
        const float* p = xyz + ((size_t)gb*NT_ + r0 + r)*3;
        float h = fmaxf(p[0]*w1x + p[1]*w1y + p[2]*w1z + bb, 0.f);
        hb[((size_t)g*NT_ + r0 + r)*C_ + t] = f2bf(h);
    }
}

// ---------------------------------------------------------------------------
// bf16 MFMA GEMM, 128 x (NF*32) tile, BK=32, 4 waves (2x2), 4 x NF fragments.
// 2-phase pipeline: dbuf LDS, STAGE(t+1) issued BEFORE compute(t), single
// trailing barrier per K-step (loads fly during ds_read+MFMA).
// XCD-grouped tile remap keeps one A-panel's col-blocks on one XCD.
// EPI 0: none, 1: relu, 2: elu+1, 4: +bias
template<int EPI, int NF>
__global__ __launch_bounds__(256)
void gemm_bf16(const short* __restrict__ A0, int lda0,
               const short* __restrict__ A1, int lda1, int split,
               const short* __restrict__ Wt,
               const float* __restrict__ bias,
               short* __restrict__ outp,
               int M, int N, int K)
{
    __shared__ __align__(16) short As[2][128*32];
    __shared__ __align__(16) short Bs[2][NF*32*32];
    int g = blockIdx.z;
    int nbs = gridDim.x, Mb = gridDim.y;
    int nb, mb;
    if ((Mb & 7) == 0) {
        int lin = blockIdx.y * nbs + blockIdx.x;
        int xcd = lin & 7, j = lin >> 3;
        nb = (j % nbs) * (NF*32);
        mb = ((j / nbs) * 8 + xcd) * 128;
    } else {
        nb = blockIdx.x * (NF*32);
        mb = blockIdx.y * 128;
    }
    int t = threadIdx.x;
    int lane = t & 63;
    int w = t >> 6, wr = w >> 1, wc = w & 1;

    const short* A0g = A0 + (size_t)g*M*lda0;
    const short* A1g = A1 ? (A1 + (size_t)g*M*lda1) : A0;

    f32x4 acc[4][NF] = {};

    int r4 = t >> 2;
    int ch = t & 3;

    auto stage = [&](int buf, int kb) {
        const short* Ab; int lda, kc;
        if (kb < split) { Ab = A0g; lda = lda0; kc = kb; }
        else            { Ab = A1g; lda = lda1; kc = kb - split; }
        const short* as0 = Ab + (size_t)(mb + r4)*lda + kc + ch*8;
        load_lds16(as0,                   &As[buf][r4*32 + ch*8]);
        load_lds16(as0 + (size_t)64*lda,  &As[buf][(r4 + 64)*32 + ch*8]);
        #pragma unroll
        for (int i = 0; i < NF/2; ++i) {
            int row = r4 + 64*i;
            load_lds16(Wt + (size_t)(nb + row)*K + kb + ch*8, &Bs[buf][row*32 + ch*8]);
        }
    };

    stage(0, 0);
    __syncthreads();
    int cur = 0;
    for (int kb = 0; kb < K; kb += 32) {
        if (kb + 32 < K) stage(cur ^ 1, kb + 32);
        int kq = (lane >> 4) * 8;
        bf16x8 af[4], bfr[NF];
        #pragma unroll
        for (int m = 0; m < 4; ++m)
            af[m] = *(const bf16x8*)&As[cur][(wr*64 + m*16 + (lane & 15))*32 + kq];
        #pragma unroll
        for (int n = 0; n < NF; ++n)
            bfr[n] = *(const bf16x8*)&Bs[cur][(wc*(NF*16) + n*16 + (lane & 15))*32 + kq];
        #pragma unroll
        for (int m = 0; m < 4; ++m)
            #pragma unroll
            for (int n = 0; n < NF; ++n)
                acc[m][n] = __builtin_amdgcn_mfma_f32_16x16x32_bf16(
                    af[m], bfr[n], acc[m][n], 0, 0, 0);
        __syncthreads();
        cur ^= 1;
    }

    short* og = outp + (size_t)g*M*N;
    int rq = (lane >> 4) * 4;
    int cl = lane & 15;
    #pragma unroll
    for (int m = 0; m < 4; ++m) {
        #pragma unroll
        for (int r = 0; r < 4; ++r) {
            int row = mb + wr*64 + m*16 + rq + r;
            size_t ro = (size_t)row * N;
            #pragma unroll
            for (int n = 0; n < NF; ++n) {
                int col = nb + wc*(NF*16) + n*16 + cl;
                float v = acc[m][n][r];
                if constexpr (EPI == 1) v = fmaxf(v, 0.f);
                if constexpr (EPI == 2) v = (v > 0.f) ? (v + 1.f) : __expf(v);
                if constexpr (EPI == 4) v = v + bias[col];
                og[ro + col] = f2bf(v);
            }
        }
    }
}

// ---------------------------------------------------------------------------
// KV[h,d,vd] partial sums over NT/NCH rows; Ksum[h,d] likewise. grid (H,NCH,G)
__global__ __launch_bounds__(256)
void kv_kernel(const short* __restrict__ Kb, const short* __restrict__ Vb,
               float* __restrict__ kvz)
{
    __shared__ float SK[32][D_];
    __shared__ float SV[32][D_];
    int h = blockIdx.x, chk = blockIdx.y, g = blockIdx.z;
    int t = threadIdx.x;
    int d = t >> 3, v0 = (t & 7) * 4;
    int lr = t >> 3, lc = (t & 7) * 4;
    float acc[4] = {0.f, 0.f, 0.f, 0.f};
    float ksum = 0.f;
    int s0beg = chk * (NT_/NCH), s0end = s0beg + NT_/NCH;
    for (int s0 = s0beg; s0 < s0end; s0 += 32) {
        size_t off = ((size_t)g*NT_ + s0 + lr)*C_ + h*D_ + lc;
        uint2 ku = *(const uint2*)(Kb + off);
        uint2 vu = *(const uint2*)(Vb + off);
        float2 k0 = bfpair(ku.x), k1 = bfpair(ku.y);
        float2 w0 = bfpair(vu.x), w1 = bfpair(vu.y);
        SK[lr][lc] = k0.x; SK[lr][lc+1] = k0.y; SK[lr][lc+2] = k1.x; SK[lr][lc+3] = k1.y;
        SV[lr][lc] = w0.x; SV[lr][lc+1] = w0.y; SV[lr][lc+2] = w1.x; SV[lr][lc+3] = w1.y;
        __syncthreads();
        #pragma unroll
        for (int ss = 0; ss < 32; ++ss) {
            float kd = SK[ss][d];
            #pragma unroll
            for (int j = 0; j < 4; ++j) acc[j] += kd * SV[ss][v0 + j];
            ksum += kd;
        }
        __syncthreads();
    }
    float* KV = kvz + ((size_t)g*NCH + chk)*KVZ_;
    #pragma unroll
    for (int j = 0; j < 4; ++j) KV[h*D_*D_ + d*D_ + v0 + j] = acc[j];
    if ((t & 7) == 0) KV[H_*D_*D_ + h*D_ + d] = ksum;
}

// ---------------------------------------------------------------------------
// reduce NCH partials -> KVT bf16 [G][h][v][d]  +  KSf f32 [G][h][d]. grid (G)
__global__ __launch_bounds__(256)
void kvfin(const float* __restrict__ kvp, short* __restrict__ KVT,
           float* __restrict__ KSf)
{
    int g = blockIdx.x, t = threadIdx.x;
    const float* p = kvp + (size_t)g*NCH*KVZ_;
    for (int idx = t; idx < H_*D_*D_; idx += 256) {
        int h = idx >> 10, rem = idx & 1023, v = rem >> 5, d = rem & 31;
        float s = 0.f;
        #pragma unroll
        for (int c = 0; c < NCH; ++c) s += p[c*KVZ_ + h*1024 + d*32 + v];
        KVT[(size_t)g*8192 + h*1024 + v*32 + d] = f2bf(s);
    }
    {
        float s = 0.f;
        #pragma unroll
        for (int c = 0; c < NCH; ++c) s += p[c*KVZ_ + H_*D_*D_ + t];
        KSf[(size_t)g*256 + t] = s;
    }
}

// ---------------------------------------------------------------------------
// Fused: Q = elu(sf@q_w)+1 ; msg = (Q (x)_h KV) * Z ; mrg = LN1(msg @ merge_w)
// Transposed products; 2-phase pipelined staging in phases 1 & 3.
__global__ __launch_bounds__(256)
void qam_kernel(const short* __restrict__ sfb, const short* __restrict__ wtq,
                const short* __restrict__ wtm, const short* __restrict__ KVT,
                const float* __restrict__ KSf,
                const float* __restrict__ ln1g, const float* __restrict__ ln1b,
                short* __restrict__ mrg)
{
    __shared__ short QT[64][264];                     // Q / msg / LN1 out
    __shared__ __align__(16) short stg[2*10240];      // dbuf: As 2048 | Bs 8192
    __shared__ float sredS[4][64], sredQ[4][64];
    __shared__ float mrM[64], mrR[64];
    __shared__ float gbet[512];

    int g = blockIdx.y;
    int l0 = blockIdx.x * 64;
    int t = threadIdx.x;
    int lane = t & 63, w = t >> 6;
    int lx = lane & 15, ly = lane >> 4;

    gbet[t]       = ln1g[t];
    gbet[256 + t] = ln1b[t];

    const short* sfg = sfb + ((size_t)g*NS_ + l0)*C_;

    auto stage1 = [&](int buf, int kb) {
        short* As = stg + buf*10240;
        short* Bs = As + 2048;
        load_lds16(sfg + (size_t)(t>>2)*C_ + kb + (t&3)*8, &As[(t>>2)*32 + (t&3)*8]);
        #pragma unroll
        for (int i = 0; i < 4; ++i) {
            int row = (t>>2) + 64*i;
            load_lds16(wtq + (size_t)row*C_ + kb + (t&3)*8, &Bs[row*32 + (t&3)*8]);
        }
    };

    // ---- phase 1: Q^T = Wq^T(A) @ sf^T(B), K=256, pipelined
    f32x4 acc[4][4] = {};
    stage1(0, 0);
    __syncthreads();
    int cur = 0;
    for (int kb = 0; kb < C_; kb += 32) {
        if (kb + 32 < C_) stage1(cur ^ 1, kb + 32);
        const short* As = stg + cur*10240;
        const short* Bs = As + 2048;
        bf16x8 af[4], bfv[4];
        #pragma unroll
        for (int m = 0; m < 4; ++m)
            af[m] = *(const bf16x8*)&Bs[(w*64 + m*16 + lx)*32 + ly*8];
        #pragma unroll
        for (int n = 0; n < 4; ++n)
            bfv[n] = *(const bf16x8*)&As[(n*16 + lx)*32 + ly*8];
        #pragma unroll
        for (int m = 0; m < 4; ++m)
            #pragma unroll
            for (int n = 0; n < 4; ++n)
                acc[m][n] = __builtin_amdgcn_mfma_f32_16x16x32_bf16(
                    af[m], bfv[n], acc[m][n], 0, 0, 0);
        __syncthreads();
        cur ^= 1;
    }
    #pragma unroll
    for (int m = 0; m < 4; ++m) {
        int c0 = w*64 + m*16 + ly*4;
        #pragma unroll
        for (int n = 0; n < 4; ++n) {
            bf16x4 pk;
            #pragma unroll
            for (int r = 0; r < 4; ++r) {
                float v = acc[m][n][r];
                pk[r] = f2bf((v > 0.f) ? (v + 1.f) : __expf(v));
            }
            *(bf16x4*)&QT[n*16 + lx][c0] = pk;
        }
    }
    __syncthreads();

    // ---- phase 2: msg^T = KV^T(A) @ Q^T(B), K=32 per head; Z via dot+shfl
    const short* kvg = KVT + (size_t)g*8192;
    bf16x8 bq[2][4];
    #pragma unroll
    for (int hh = 0; hh < 2; ++hh)
        #pragma unroll
        for (int n = 0; n < 4; ++n)
            bq[hh][n] = *(const bf16x8*)&QT[n*16 + lx][(2*w + hh)*32 + ly*8];
    float z[2][4];
    #pragma unroll
    for (int hh = 0; hh < 2; ++hh) {
        const float* kp = KSf + (size_t)g*256 + (2*w + hh)*32 + ly*8;
        float4 ka = *(const float4*)kp;
        float4 kb4 = *(const float4*)(kp + 4);
        float kr[8] = {ka.x, ka.y, ka.z, ka.w, kb4.x, kb4.y, kb4.z, kb4.w};
        #pragma unroll
        for (int n = 0; n < 4; ++n) {
            float s = 0.f;
            #pragma unroll
            for (int j = 0; j < 8; ++j) s += bf2f(bq[hh][n][j]) * kr[j];
            s += __shfl_xor(s, 16);
            s += __shfl_xor(s, 32);
            z[hh][n] = 1.f / (s + 1e-6f);
        }
    }
    f32x4 zero = {0.f, 0.f, 0.f, 0.f};
    f32x4 a2[4][4];
    #pragma unroll
    for (int m = 0; m < 4; ++m) {
        int h = 2*w + (m >> 1);
        bf16x8 afk = *(const bf16x8*)(kvg + ((size_t)h*1024 + ((m&1)*16 + lx)*32 + ly*8));
        #pragma unroll
        for (int n = 0; n < 4; ++n)
            a2[m][n] = __builtin_amdgcn_mfma_f32_16x16x32_bf16(
                afk, bq[m>>1][n], zero, 0, 0, 0);
    }
    #pragma unroll
    for (int m = 0; m < 4; ++m) {
        int c0 = w*64 + m*16 + ly*4;
        #pragma unroll
        for (int n = 0; n < 4; ++n) {
            bf16x4 pk;
            #pragma unroll
            for (int r = 0; r < 4; ++r)
                pk[r] = f2bf(a2[m][n][r] * z[m>>1][n]);
            *(bf16x4*)&QT[n*16 + lx][c0] = pk;
        }
    }
    __syncthreads();

    // ---- phase 3: mrg^T = Wm^T(A) @ msg^T(B), K=256, pipelined (Bs only)
    auto stage3 = [&](int buf, int kb) {
        short* Bs = stg + buf*10240 + 2048;
        #pragma unroll
        for (int i = 0; i < 4; ++i) {
            int row = (t>>2) + 64*i;
            load_lds16(wtm + (size_t)row*C_ + kb + (t&3)*8, &Bs[row*32 + (t&3)*8]);
        }
    };
    f32x4 acc3[4][4] = {};
    stage3(0, 0);
    __syncthreads();
    cur = 0;
    for (int kb = 0; kb < C_; kb += 32) {
        if (kb + 32 < C_) stage3(cur ^ 1, kb + 32);
        const short* Bs = stg + cur*10240 + 2048;
        bf16x8 af[4], bfv[4];
        #pragma unroll
        for (int m = 0; m < 4; ++m)
            af[m] = *(const bf16x8*)&Bs[(w*64 + m*16 + lx)*32 + ly*8];
        #pragma unroll
        for (int n = 0; n < 4; ++n)
            bfv[n] = *(const bf16x8*)&QT[n*16 + lx][kb + ly*8];
        #pragma unroll
        for (int m = 0; m < 4; ++m)
            #pragma unroll
            for (int n = 0; n < 4; ++n)
                acc3[m][n] = __builtin_amdgcn_mfma_f32_16x16x32_bf16(
                    af[m], bfv[n], acc3[m][n], 0, 0, 0);
        __syncthreads();
        cur ^= 1;
    }

    // ---- LN1 over channels (f32 accs)
    float sP[4] = {0,0,0,0}, qP[4] = {0,0,0,0};
    #pragma unroll
    for (int n = 0; n < 4; ++n)
        #pragma unroll
        for (int m = 0; m < 4; ++m)
            #pragma unroll
            for (int r = 0; r < 4; ++r) {
                float v = acc3[m][n][r];
                sP[n] += v; qP[n] += v*v;
            }
    #pragma unroll
    for (int n = 0; n < 4; ++n) {
        sP[n] += __shfl_xor(sP[n], 16); sP[n] += __shfl_xor(sP[n], 32);
        qP[n] += __shfl_xor(qP[n], 16); qP[n] += __shfl_xor(qP[n], 32);
    }
    if (ly == 0) {
        #pragma unroll
        for (int n = 0; n < 4; ++n) {
            sredS[w][n*16 + lx] = sP[n];
            sredQ[w][n*16 + lx] = qP[n];
        }
    }
    __syncthreads();
    if (t < 64) {
        float s = 0.f, q = 0.f;
        #pragma unroll
        for (int ww = 0; ww < 4; ++ww) { s += sredS[ww][t]; q += sredQ[ww][t]; }
        float m = s * (1.f/C_);
        mrM[t] = m;
        mrR[t] = rsqrtf(q*(1.f/C_) - m*m + 1e-5f);
    }
    __syncthreads();
    #pragma unroll
    for (int n = 0; n < 4; ++n) {
        float mn = mrM[n*16 + lx], rs = mrR[n*16 + lx];
        #pragma unroll
        for (int m = 0; m < 4; ++m) {
            int c0 = w*64 + m*16 + ly*4;
            bf16x4 pk;
            #pragma unroll
            for (int r = 0; r < 4; ++r) {
                int c = c0 + r;
                pk[r] = f2bf((acc3[m][n][r] - mn)*rs*gbet[c] + gbet[256 + c]);
            }
            *(bf16x4*)&QT[n*16 + lx][c0] = pk;
        }
    }
    __syncthreads();
    short* og = mrg + ((size_t)g*NS_ + l0)*C_;
    int row = t >> 2;
    #pragma unroll
    for (int i = 0; i < 8; ++i) {
        int chk = (t & 3) + 4*i;
        *(uint4*)(og + (size_t)row*C_ + chk*8) = *(const uint4*)&QT[row][chk*8];
    }
}

// ---------------------------------------------------------------------------
// Fused mlp2 + LN2 + residual + transpose, 2-phase pipelined.
__global__ __launch_bounds__(256, 4)
void m2f_kernel(const short* __restrict__ hid, const short* __restrict__ wt2,
                const float* __restrict__ sfeat,
                const float* __restrict__ ln2g, const float* __restrict__ ln2b,
                float* __restrict__ out, int b0)
{
    __shared__ __align__(16) short sh[2*10240];  // dbuf As 8192|Bs 2048; later QTm
    __shared__ float sredS[4][64], sredQ[4][64];
    __shared__ float mrM[64], mrR[64];
    __shared__ float gbet[512];

    int g = blockIdx.y, gb = b0 + g;
    int l0 = blockIdx.x * 64;
    int t = threadIdx.x;
    int lane = t & 63, w = t >> 6;
    int lx = lane & 15, ly = lane >> 4;

    gbet[t]       = ln2g[t];
    gbet[256 + t] = ln2b[t];

    const short* hg = hid + ((size_t)g*NS_ + l0)*C2_;

    auto stage = [&](int buf, int kb) {
        short* As = sh + buf*10240;
        short* Bs = As + 8192;
        #pragma unroll
        for (int i = 0; i < 4; ++i) {
            int row = (t>>2) + 64*i;
            load_lds16(wt2 + (size_t)row*C2_ + kb + (t&3)*8, &As[row*32 + (t&3)*8]);
        }
        load_lds16(hg + (size_t)(t>>2)*C2_ + kb + (t&3)*8, &Bs[(t>>2)*32 + (t&3)*8]);
    };

    f32x4 acc[4][4] = {};
    stage(0, 0);
    __syncthreads();
    int cur = 0;
    for (int kb = 0; kb < C2_; kb += 32) {
        if (kb + 32 < C2_) stage(cur ^ 1, kb + 32);
        const short* As = sh + cur*10240;
        const short* Bs = As + 8192;
        bf16x8 af[4], bfv[4];
        #pragma unroll
        for (int m = 0; m < 4; ++m)
            af[m] = *(const bf16x8*)&As[(w*64 + m*16 + lx)*32 + ly*8];
        #pragma unroll
        for (int n = 0; n < 4; ++n)
            bfv[n] = *(const bf16x8*)&Bs[(n*16 + lx)*32 + ly*8];
        #pragma unroll
        for (int m = 0; m < 4; ++m)
            #pragma unroll
            for (int n = 0; n < 4; ++n)
                acc[m][n] = __builtin_amdgcn_mfma_f32_16x16x32_bf16(
                    af[m], bfv[n], acc[m][n], 0, 0, 0);
        __syncthreads();
        cur ^= 1;
    }

    // LN2 reduction over channels (f32 accs)
    float sP[4] = {0,0,0,0}, qP[4] = {0,0,0,0};
    #pragma unroll
    for (int n = 0; n < 4; ++n)
        #pragma unroll
        for (int m = 0; m < 4; ++m)
            #pragma unroll
            for (int r = 0; r < 4; ++r) {
                float v = acc[m][n][r];
                sP[n] += v; qP[n] += v*v;
            }
    #pragma unroll
    for (int n = 0; n < 4; ++n) {
        sP[n] += __shfl_xor(sP[n], 16); sP[n] += __shfl_xor(sP[n], 32);
        qP[n] += __shfl_xor(qP[n], 16); qP[n] += __shfl_xor(qP[n], 32);
    }
    if (ly == 0) {
        #pragma unroll
        for (int n = 0; n < 4; ++n) {
            sredS[w][n*16 + lx] = sP[n];
            sredQ[w][n*16 + lx] = qP[n];
        }
    }
    __syncthreads();
    if (t < 64) {
        float s = 0.f, q = 0.f;
        #pragma unroll
        for (int ww = 0; ww < 4; ++ww) { s += sredS[ww][t]; q += sredQ[ww][t]; }
        float m = s * (1.f/C_);
        mrM[t] = m;
        mrR[t] = rsqrtf(q*(1.f/C_) - m*m + 1e-5f);
    }
    __syncthreads();

    // pack normalized bf16 into QTm (overlays staging; dead)
    #pragma unroll
    for (int n = 0; n < 4; ++n) {
        int l = n*16 + lx;
        float mn = mrM[l], rs = mrR[l];
        #pragma unroll
        for (int m = 0; m < 4; ++m) {
            int c0 = w*64 + m*16 + ly*4;
            #pragma unroll
            for (int r = 0; r < 4; ++r)
                sh[l*258 + c0 + r] =
                    f2bf((acc[m][n][r] - mn)*rs*gbet[c0+r] + gbet[256 + c0 + r]);
        }
    }
    __syncthreads();

    // coalesced residual + f32 store
    int l = t & 63, cg = t >> 6;
    const float* sfp = sfeat + (size_t)gb*C_*NS_ + l0;
    float* op = out + (size_t)gb*C_*NS_ + l0;
    for (int ci = 0; ci < 64; ++ci) {
        int c = cg*64 + ci;
        size_t o = (size_t)c*NS_ + l;
        op[o] = sfp[o] + bf2f(sh[l*258 + c]);
    }
}

// ---------------------------------------------------------------------------
extern "C" void kernel_launch(void* const* d_in, const int* in_sizes, int n_in,
                              void* d_out, int out_size, void* d_ws, size_t ws_size,
                              hipStream_t stream)
{
    (void)in_sizes; (void)n_in; (void)out_size;
    const float* search_feat   = (const float*)d_in[0];
    const float* template_feat = (const float*)d_in[2];
    const float* template_xyz  = (const float*)d_in[3];
    const float* pos_w1  = (const float*)d_in[4];
    const float* pos_b1  = (const float*)d_in[5];
    const float* pos_w2  = (const float*)d_in[6];
    const float* pos_b2  = (const float*)d_in[7];
    const float* q_w     = (const float*)d_in[8];
    const float* k_w     = (const float*)d_in[9];
    const float* v_w     = (const float*)d_in[10];
    const float* merge_w = (const float*)d_in[11];
    const float* mlp_w1  = (const float*)d_in[12];
    const float* mlp_w2  = (const float*)d_in[13];
    const float* ln1_g   = (const float*)d_in[14];
    const float* ln1_b   = (const float*)d_in[15];
    const float* ln2_g   = (const float*)d_in[16];
    const float* ln2_b   = (const float*)d_in[17];
    float* out = (float*)d_out;

    const int W_Q = 0, W_K = 65536, W_M = 131072, W_P = 196608,
              W_1 = 262144, W_2 = 524288, W_V2 = 655360;
    const size_t wElems = 786432;

    size_t sfE = (size_t)NS_*C_, tfE = (size_t)NT_*C_;
    int G = 8;
    while (G > 1) {
        size_t shorts = (size_t)G*(4*sfE + tfE + 8192) + wElems;
        size_t bytes  = shorts*2 + (size_t)G*(NCH*KVZ_ + 256)*4 + 256*4 + 1024;
        if (bytes <= ws_size) break;
        G >>= 1;
    }

    short* wtb  = (short*)d_ws;
    short* sfb  = wtb  + wElems;          // [G,NS,C]
    short* tfb  = sfb  + (size_t)G*sfE;   // [G,NT,C]
    short* hid  = tfb  + (size_t)G*tfE;   // [G,NS,2C]; early: K | V | h
    short* mrgb = hid  + (size_t)2*G*sfE; // [G,NS,C]  LN1(merge) out
    short* KVTb = mrgb + (size_t)G*sfE;   // [G,8192]
    float* kvpf = (float*)(KVTb + (size_t)G*8192);
    float* KSfb = kvpf + (size_t)G*NCH*KVZ_;
    float* bvf  = KSfb + (size_t)G*256;
    short* Kb = hid;
    short* Vb = hid + (size_t)G*tfE;
    short* hb = hid + (size_t)2*G*tfE;    // pos-mlp hidden h [G,NT,C]

    WPack pack;
    pack.d[0] = { q_w,     C_,  C_,  W_Q,  C_  };
    pack.d[1] = { k_w,     C_,  C_,  W_K,  C_  };
    pack.d[2] = { merge_w, C_,  C_,  W_M,  C_  };
    pack.d[3] = { pos_w2,  C_,  C_,  W_P,  C_  };
    pack.d[4] = { mlp_w1,  C2_, C2_, W_1,  C2_ };
    pack.d[5] = { mlp_w2,  C2_, C_,  W_2,  C2_ };
    pack.d[6] = { v_w,     C_,  C_,  W_V2, C2_ };  // first half of fused V
    wcast_all<<<dim3(16, 16, 7), 256, 0, stream>>>(pack, wtb);
    fusew<<<dim3(256), 256, 0, stream>>>(wtb + W_V2, wtb + W_P, pos_b2, v_w, bvf);

    for (int b0 = 0; b0 < B_; b0 += G) {
        castT<<<dim3(NS_/32, C_/32, G), 256, 0, stream>>>(search_feat, sfb, NS_, b0);
        castT<<<dim3(NT_/32, C_/32, G), 256, 0, stream>>>(template_feat, tfb, NT_, b0);
        pos_h<<<dim3(NT_/16, G), 256, 0, stream>>>(template_xyz, pos_w1, pos_b1, hb, b0);
        // K = elu(tf @ k_w)+1
        gemm_bf16<2,4><<<dim3(C_/128, NT_/128, G), 256, 0, stream>>>(
            tfb, C_, nullptr, 0, 1<<30, wtb + W_K, nullptr, Kb, NT_, C_, C_);
        // V = [tf | h] @ [v_w ; posw2@v_w] + (b2@v_w)
        gemm_bf16<4,4><<<dim3(C_/128, NT_/128, G), 256, 0, stream>>>(
            tfb, C_, hb, C_, C_, wtb + W_V2, bvf, Vb, NT_, C_, C2_);
        kv_kernel<<<dim3(H_, NCH, G), 256, 0, stream>>>(Kb, Vb, kvpf);
        kvfin<<<dim3(G), 256, 0, stream>>>(kvpf, KVTb, KSfb);
        // fused Q -> attn -> merge -> LN1
        qam_kernel<<<dim3(NS_/64, G), 256, 0, stream>>>(
            sfb, wtb + W_Q, wtb + W_M, KVTb, KSfb, ln1_g, ln1_b, mrgb);
        // hidden = relu([sf | mrg] @ mlp_w1)
        gemm_bf16<1,4><<<dim3(C2_/128, NS_/128, G), 256, 0, stream>>>(
            sfb, C_, mrgb, C_, C_, wtb + W_1, nullptr, hid, NS_, C2_, C2_);
        // fused mlp2 + LN2 + residual + transpose
        m2f_kernel<<<dim3(NS_/64, G), 256, 0, stream>>>(
            hid, wtb + W_2, search_feat, ln2_g, ln2_b, out, b0);
    }
}

// Round 9
// 526.363 us; speedup vs baseline: 1.4016x; 1.0007x over previous
//
#include <hip/hip_runtime.h>
#include <math.h>

#define B_  8
#define C_  256
#define NS_ 16384
#define NT_ 8192
#define H_  8
#define D_  32
#define C2_ 512
#define NCH 4
#define KVZ_ (H_*D_*D_ + H_*D_)   // 8448 floats per (batch, chunk)

typedef __attribute__((ext_vector_type(8))) short bf16x8;
typedef __attribute__((ext_vector_type(4))) short bf16x4;
typedef __attribute__((ext_vector_type(4))) float f32x4;

// Leading sync: counted vmcnt keeps prefetches in flight across the barrier.
#define PIPE_TOP(N) do {                                              \
    asm volatile("s_waitcnt vmcnt(" #N ")" ::: "memory");             \
    asm volatile("s_barrier" ::: "memory");                           \
    __builtin_amdgcn_sched_barrier(0);                                \
} while (0)
// Trailing sync hardened per rule #18: sched_barrier pins the MFMA cluster
// (register-only -> not ordered by "memory") above the barrier; lgkmcnt(0)
// drains straggler ds_reads; vmcnt prefetches remain in flight.
#define PIPE_BOT() do {                                               \
    __builtin_amdgcn_sched_barrier(0);                                \
    asm volatile("s_waitcnt lgkmcnt(0)" ::: "memory");                \
    asm volatile("s_barrier" ::: "memory");                           \
} while (0)

__device__ __forceinline__ short f2bf(float f) {
    unsigned u = __float_as_uint(f);
    u = (u + 0x7fffu + ((u >> 16) & 1u)) >> 16;
    return (short)u;
}
__device__ __forceinline__ float bf2f(short s) {
    return __uint_as_float(((unsigned)(unsigned short)s) << 16);
}
__device__ __forceinline__ float2 bfpair(unsigned u) {
    float2 r;
    r.x = __uint_as_float(u << 16);
    r.y = __uint_as_float(u & 0xffff0000u);
    return r;
}
__device__ __forceinline__ void load_lds16(const void* g, void* l) {
    __builtin_amdgcn_global_load_lds(
        (const __attribute__((address_space(1))) unsigned int*)g,
        (__attribute__((address_space(3))) unsigned int*)l, 16, 0, 0);
}

// ---------------------------------------------------------------------------
// transpose-cast: in [B, C, NLEN] f32 -> ob [G, NLEN, C] bf16
__global__ __launch_bounds__(256)
void castT(const float* __restrict__ in, short* __restrict__ ob, int NLEN, int b0)
{
    __shared__ float tl[32][33];
    int g = blockIdx.z, gb = b0 + g;
    int n0 = blockIdx.x * 32, c0 = blockIdx.y * 32;
    int t = threadIdx.x, tr = t >> 5, tc = t & 31;
    #pragma unroll
    for (int i = 0; i < 4; ++i)
        tl[tr + 8*i][tc] = in[((size_t)gb*C_ + c0 + tr + 8*i)*NLEN + n0 + tc];
    __syncthreads();
    #pragma unroll
    for (int i = 0; i < 4; ++i)
        ob[((size_t)g*NLEN + n0 + tr + 8*i)*C_ + c0 + tc] = f2bf(tl[tc][tr + 8*i]);
}

// ---------------------------------------------------------------------------
// weight transpose-cast: w [K,N] f32 -> wt[off + n*ldo + k] bf16
struct WDesc { const float* src; int K; int N; int off; int ldo; };
struct WPack { WDesc d[7]; };

__global__ __launch_bounds__(256)
void wcast_all(WPack p, short* __restrict__ wt)
{
    __shared__ float tl[32][33];
    WDesc d = p.d[blockIdx.z];
    int kt = blockIdx.x * 32, nt = blockIdx.y * 32;
    if (kt >= d.K || nt >= d.N) return;
    int t = threadIdx.x, tr = t >> 5, tc = t & 31;
    #pragma unroll
    for (int i = 0; i < 4; ++i)
        tl[tr + 8*i][tc] = d.src[(size_t)(kt + tr + 8*i)*d.N + nt + tc];
    __syncthreads();
    short* o = wt + d.off;
    #pragma unroll
    for (int i = 0; i < 4; ++i)
        o[(size_t)(nt + tr + 8*i)*d.ldo + kt + tc] = f2bf(tl[tc][tr + 8*i]);
}

// ---------------------------------------------------------------------------
// fused V-weight: Wv2[n, 256+k] = sum_m v_w[m,n]*posw2[k,m];  bv[n] = b2 @ v_w
__global__ __launch_bounds__(256)
void fusew(short* __restrict__ wv2, const short* __restrict__ wp,
           const float* __restrict__ b2, const float* __restrict__ v_w,
           float* __restrict__ bv)
{
    int n = blockIdx.x, k = threadIdx.x;
    __shared__ float vrow[256];
    __shared__ float bred[256];
    vrow[k] = bf2f(wv2[(size_t)n*512 + k]);
    bred[k] = b2[k] * v_w[(size_t)k*C_ + n];
    __syncthreads();
    float s = 0.f;
    for (int m = 0; m < 256; ++m)
        s += vrow[m] * bf2f(wp[m*256 + k]);
    wv2[(size_t)n*512 + 256 + k] = f2bf(s);
    for (int off2 = 128; off2 > 0; off2 >>= 1) {
        __syncthreads();
        if (k < off2) bred[k] += bred[k + off2];
    }
    if (k == 0) bv[n] = bred[0];
}

// ---------------------------------------------------------------------------
// h = relu(xyz @ w1 + b1) -> bf16 [G, NT, C]
__global__ __launch_bounds__(256)
void pos_h(const float* __restrict__ xyz, const float* __restrict__ w1,
           const float* __restrict__ b1, short* __restrict__ hb, int b0)
{
    int g = blockIdx.y, gb = b0 + g;
    int r0 = blockIdx.x * 16;
    int t = threadIdx.x;
    float w1x = w1[t], w1y = w1[C_ + t], w1z = w1[2*C_ + t], bb = b1[t];
    for (int r = 0; r < 16; ++r) {
        const float* p = xyz + ((size_t)gb*NT_ + r0 + r)*3;
        float h = fmaxf(p[0]*w1x + p[1]*w1y + p[2]*w1z + bb, 0.f);
        hb[((size_t)g*NT_ + r0 + r)*C_ + t] = f2bf(h);
    }
}

// ---------------------------------------------------------------------------
// bf16 MFMA GEMM, 128 x (NF*32) tile, BK=32, 4 waves (2x2), 4 x NF fragments.
// 3-deep counted-vmcnt pipeline (T4) with rule-#18-hardened barriers.
// XCD-grouped tile remap keeps one A-panel's col-blocks on one XCD.
// EPI 0: none, 1: relu, 2: elu+1, 4: +bias
template<int EPI, int NF>
__global__ __launch_bounds__(256)
void gemm_bf16(const short* __restrict__ A0, int lda0,
               const short* __restrict__ A1, int lda1, int split,
               const short* __restrict__ Wt,
               const float* __restrict__ bias,
               short* __restrict__ outp,
               int M, int N, int K)
{
    __shared__ __align__(16) short As[3][128*32];
    __shared__ __align__(16) short Bs[3][NF*32*32];
    int g = blockIdx.z;
    int nbs = gridDim.x, Mb = gridDim.y;
    int nb, mb;
    if ((Mb & 7) == 0) {
        int lin = blockIdx.y * nbs + blockIdx.x;
        int xcd = lin & 7, j = lin >> 3;
        nb = (j % nbs) * (NF*32);
        mb = ((j / nbs) * 8 + xcd) * 128;
    } else {
        nb = blockIdx.x * (NF*32);
        mb = blockIdx.y * 128;
    }
    int t = threadIdx.x;
    int lane = t & 63;
    int w = t >> 6, wr = w >> 1, wc = w & 1;

    const short* A0g = A0 + (size_t)g*M*lda0;
    const short* A1g = A1 ? (A1 + (size_t)g*M*lda1) : A0;

    f32x4 acc[4][NF] = {};

    int r4 = t >> 2;
    int ch = t & 3;

    // 4 loads/thread per stage (2 A + NF/2 B)
    auto stage = [&](int buf, int kb) {
        const short* Ab; int lda, kc;
        if (kb < split) { Ab = A0g; lda = lda0; kc = kb; }
        else            { Ab = A1g; lda = lda1; kc = kb - split; }
        const short* as0 = Ab + (size_t)(mb + r4)*lda + kc + ch*8;
        load_lds16(as0,                   &As[buf][r4*32 + ch*8]);
        load_lds16(as0 + (size_t)64*lda,  &As[buf][(r4 + 64)*32 + ch*8]);
        #pragma unroll
        for (int i = 0; i < NF/2; ++i) {
            int row = r4 + 64*i;
            load_lds16(Wt + (size_t)(nb + row)*K + kb + ch*8, &Bs[buf][row*32 + ch*8]);
        }
    };

    int T = K >> 5;
    stage(0, 0);
    if (T > 1) stage(1, 32);
    int cur = 0;
    for (int tt = 0; tt < T; ++tt) {
        if (tt + 2 < T) {
            int st = (cur >= 1) ? cur - 1 : 2;   // (cur+2)%3
            stage(st, (tt + 2) << 5);
            PIPE_TOP(8);                          // stage(tt) landed; 2 in flight
        } else if (tt + 1 < T) {
            PIPE_TOP(4);
        } else {
            PIPE_TOP(0);
        }
        int kq = (lane >> 4) * 8;
        bf16x8 af[4], bfr[NF];
        #pragma unroll
        for (int m = 0; m < 4; ++m)
            af[m] = *(const bf16x8*)&As[cur][(wr*64 + m*16 + (lane & 15))*32 + kq];
        #pragma unroll
        for (int n = 0; n < NF; ++n)
            bfr[n] = *(const bf16x8*)&Bs[cur][(wc*(NF*16) + n*16 + (lane & 15))*32 + kq];
        #pragma unroll
        for (int m = 0; m < 4; ++m)
            #pragma unroll
            for (int n = 0; n < NF; ++n)
                acc[m][n] = __builtin_amdgcn_mfma_f32_16x16x32_bf16(
                    af[m], bfr[n], acc[m][n], 0, 0, 0);
        PIPE_BOT();                               // reads drained before overwrite
        cur = (cur == 2) ? 0 : cur + 1;
    }

    short* og = outp + (size_t)g*M*N;
    int rq = (lane >> 4) * 4;
    int cl = lane & 15;
    #pragma unroll
    for (int m = 0; m < 4; ++m) {
        #pragma unroll
        for (int r = 0; r < 4; ++r) {
            int row = mb + wr*64 + m*16 + rq + r;
            size_t ro = (size_t)row * N;
            #pragma unroll
            for (int n = 0; n < NF; ++n) {
                int col = nb + wc*(NF*16) + n*16 + cl;
                float v = acc[m][n][r];
                if constexpr (EPI == 1) v = fmaxf(v, 0.f);
                if constexpr (EPI == 2) v = (v > 0.f) ? (v + 1.f) : __expf(v);
                if constexpr (EPI == 4) v = v + bias[col];
                og[ro + col] = f2bf(v);
            }
        }
    }
}

// ---------------------------------------------------------------------------
// KV[h,d,vd] partial sums over NT/NCH rows; Ksum[h,d] likewise. grid (H,NCH,G)
__global__ __launch_bounds__(256)
void kv_kernel(const short* __restrict__ Kb, const short* __restrict__ Vb,
               float* __restrict__ kvz)
{
    __shared__ float SK[32][D_];
    __shared__ float SV[32][D_];
    int h = blockIdx.x, chk = blockIdx.y, g = blockIdx.z;
    int t = threadIdx.x;
    int d = t >> 3, v0 = (t & 7) * 4;
    int lr = t >> 3, lc = (t & 7) * 4;
    float acc[4] = {0.f, 0.f, 0.f, 0.f};
    float ksum = 0.f;
    int s0beg = chk * (NT_/NCH), s0end = s0beg + NT_/NCH;
    for (int s0 = s0beg; s0 < s0end; s0 += 32) {
        size_t off = ((size_t)g*NT_ + s0 + lr)*C_ + h*D_ + lc;
        uint2 ku = *(const uint2*)(Kb + off);
        uint2 vu = *(const uint2*)(Vb + off);
        float2 k0 = bfpair(ku.x), k1 = bfpair(ku.y);
        float2 w0 = bfpair(vu.x), w1 = bfpair(vu.y);
        SK[lr][lc] = k0.x; SK[lr][lc+1] = k0.y; SK[lr][lc+2] = k1.x; SK[lr][lc+3] = k1.y;
        SV[lr][lc] = w0.x; SV[lr][lc+1] = w0.y; SV[lr][lc+2] = w1.x; SV[lr][lc+3] = w1.y;
        __syncthreads();
        #pragma unroll
        for (int ss = 0; ss < 32; ++ss) {
            float kd = SK[ss][d];
            #pragma unroll
            for (int j = 0; j < 4; ++j) acc[j] += kd * SV[ss][v0 + j];
            ksum += kd;
        }
        __syncthreads();
    }
    float* KV = kvz + ((size_t)g*NCH + chk)*KVZ_;
    #pragma unroll
    for (int j = 0; j < 4; ++j) KV[h*D_*D_ + d*D_ + v0 + j] = acc[j];
    if ((t & 7) == 0) KV[H_*D_*D_ + h*D_ + d] = ksum;
}

// ---------------------------------------------------------------------------
// reduce NCH partials -> KVT bf16 [G][h][v][d]  +  KSf f32 [G][h][d]. grid (G)
__global__ __launch_bounds__(256)
void kvfin(const float* __restrict__ kvp, short* __restrict__ KVT,
           float* __restrict__ KSf)
{
    int g = blockIdx.x, t = threadIdx.x;
    const float* p = kvp + (size_t)g*NCH*KVZ_;
    for (int idx = t; idx < H_*D_*D_; idx += 256) {
        int h = idx >> 10, rem = idx & 1023, v = rem >> 5, d = rem & 31;
        float s = 0.f;
        #pragma unroll
        for (int c = 0; c < NCH; ++c) s += p[c*KVZ_ + h*1024 + d*32 + v];
        KVT[(size_t)g*8192 + h*1024 + v*32 + d] = f2bf(s);
    }
    {
        float s = 0.f;
        #pragma unroll
        for (int c = 0; c < NCH; ++c) s += p[c*KVZ_ + H_*D_*D_ + t];
        KSf[(size_t)g*256 + t] = s;
    }
}

// ---------------------------------------------------------------------------
// Fused: Q = elu(sf@q_w)+1 ; msg = (Q (x)_h KV) * Z ; mrg = LN1(msg @ merge_w)
// Transposed products; round-6 proven 2-phase dbuf with __syncthreads.
__global__ __launch_bounds__(256)
void qam_kernel(const short* __restrict__ sfb, const short* __restrict__ wtq,
                const short* __restrict__ wtm, const short* __restrict__ KVT,
                const float* __restrict__ KSf,
                const float* __restrict__ ln1g, const float* __restrict__ ln1b,
                short* __restrict__ mrg)
{
    __shared__ short QT[64][264];                     // Q / msg / LN1 out
    __shared__ __align__(16) short stg[2*10240];      // dbuf: As 2048 | Bs 8192
    __shared__ float sredS[4][64], sredQ[4][64];
    __shared__ float mrM[64], mrR[64];
    __shared__ float gbet[512];

    int g = blockIdx.y;
    int l0 = blockIdx.x * 64;
    int t = threadIdx.x;
    int lane = t & 63, w = t >> 6;
    int lx = lane & 15, ly = lane >> 4;

    gbet[t]       = ln1g[t];
    gbet[256 + t] = ln1b[t];

    const short* sfg = sfb + ((size_t)g*NS_ + l0)*C_;

    auto stage1 = [&](int buf, int kb) {
        short* As = stg + buf*10240;
        short* Bs = As + 2048;
        load_lds16(sfg + (size_t)(t>>2)*C_ + kb + (t&3)*8, &As[(t>>2)*32 + (t&3)*8]);
        #pragma unroll
        for (int i = 0; i < 4; ++i) {
            int row = (t>>2) + 64*i;
            load_lds16(wtq + (size_t)row*C_ + kb + (t&3)*8, &Bs[row*32 + (t&3)*8]);
        }
    };

    // ---- phase 1: Q^T = Wq^T(A) @ sf^T(B), K=256
    f32x4 acc[4][4] = {};
    stage1(0, 0);
    __syncthreads();
    int cur = 0;
    for (int kb = 0; kb < C_; kb += 32) {
        if (kb + 32 < C_) stage1(cur ^ 1, kb + 32);
        const short* As = stg + cur*10240;
        const short* Bs = As + 2048;
        bf16x8 af[4], bfv[4];
        #pragma unroll
        for (int m = 0; m < 4; ++m)
            af[m] = *(const bf16x8*)&Bs[(w*64 + m*16 + lx)*32 + ly*8];
        #pragma unroll
        for (int n = 0; n < 4; ++n)
            bfv[n] = *(const bf16x8*)&As[(n*16 + lx)*32 + ly*8];
        #pragma unroll
        for (int m = 0; m < 4; ++m)
            #pragma unroll
            for (int n = 0; n < 4; ++n)
                acc[m][n] = __builtin_amdgcn_mfma_f32_16x16x32_bf16(
                    af[m], bfv[n], acc[m][n], 0, 0, 0);
        __syncthreads();
        cur ^= 1;
    }
    #pragma unroll
    for (int m = 0; m < 4; ++m) {
        int c0 = w*64 + m*16 + ly*4;
        #pragma unroll
        for (int n = 0; n < 4; ++n) {
            bf16x4 pk;
            #pragma unroll
            for (int r = 0; r < 4; ++r) {
                float v = acc[m][n][r];
                pk[r] = f2bf((v > 0.f) ? (v + 1.f) : __expf(v));
            }
            *(bf16x4*)&QT[n*16 + lx][c0] = pk;
        }
    }
    __syncthreads();

    // ---- phase 2: msg^T = KV^T(A) @ Q^T(B), K=32 per head; Z via dot+shfl
    const short* kvg = KVT + (size_t)g*8192;
    bf16x8 bq[2][4];
    #pragma unroll
    for (int hh = 0; hh < 2; ++hh)
        #pragma unroll
        for (int n = 0; n < 4; ++n)
            bq[hh][n] = *(const bf16x8*)&QT[n*16 + lx][(2*w + hh)*32 + ly*8];
    float z[2][4];
    #pragma unroll
    for (int hh = 0; hh < 2; ++hh) {
        const float* kp = KSf + (size_t)g*256 + (2*w + hh)*32 + ly*8;
        float4 ka = *(const float4*)kp;
        float4 kb4 = *(const float4*)(kp + 4);
        float kr[8] = {ka.x, ka.y, ka.z, ka.w, kb4.x, kb4.y, kb4.z, kb4.w};
        #pragma unroll
        for (int n = 0; n < 4; ++n) {
            float s = 0.f;
            #pragma unroll
            for (int j = 0; j < 8; ++j) s += bf2f(bq[hh][n][j]) * kr[j];
            s += __shfl_xor(s, 16);
            s += __shfl_xor(s, 32);
            z[hh][n] = 1.f / (s + 1e-6f);
        }
    }
    f32x4 zero = {0.f, 0.f, 0.f, 0.f};
    f32x4 a2[4][4];
    #pragma unroll
    for (int m = 0; m < 4; ++m) {
        int h = 2*w + (m >> 1);
        bf16x8 afk = *(const bf16x8*)(kvg + ((size_t)h*1024 + ((m&1)*16 + lx)*32 + ly*8));
        #pragma unroll
        for (int n = 0; n < 4; ++n)
            a2[m][n] = __builtin_amdgcn_mfma_f32_16x16x32_bf16(
                afk, bq[m>>1][n], zero, 0, 0, 0);
    }
    #pragma unroll
    for (int m = 0; m < 4; ++m) {
        int c0 = w*64 + m*16 + ly*4;
        #pragma unroll
        for (int n = 0; n < 4; ++n) {
            bf16x4 pk;
            #pragma unroll
            for (int r = 0; r < 4; ++r)
                pk[r] = f2bf(a2[m][n][r] * z[m>>1][n]);
            *(bf16x4*)&QT[n*16 + lx][c0] = pk;
        }
    }
    __syncthreads();

    // ---- phase 3: mrg^T = Wm^T(A) @ msg^T(B), K=256 (Bs only)
    auto stage3 = [&](int buf, int kb) {
        short* Bs = stg + buf*10240 + 2048;
        #pragma unroll
        for (int i = 0; i < 4; ++i) {
            int row = (t>>2) + 64*i;
            load_lds16(wtm + (size_t)row*C_ + kb + (t&3)*8, &Bs[row*32 + (t&3)*8]);
        }
    };
    f32x4 acc3[4][4] = {};
    stage3(0, 0);
    __syncthreads();
    cur = 0;
    for (int kb = 0; kb < C_; kb += 32) {
        if (kb + 32 < C_) stage3(cur ^ 1, kb + 32);
        const short* Bs = stg + cur*10240 + 2048;
        bf16x8 af[4], bfv[4];
        #pragma unroll
        for (int m = 0; m < 4; ++m)
            af[m] = *(const bf16x8*)&Bs[(w*64 + m*16 + lx)*32 + ly*8];
        #pragma unroll
        for (int n = 0; n < 4; ++n)
            bfv[n] = *(const bf16x8*)&QT[n*16 + lx][kb + ly*8];
        #pragma unroll
        for (int m = 0; m < 4; ++m)
            #pragma unroll
            for (int n = 0; n < 4; ++n)
                acc3[m][n] = __builtin_amdgcn_mfma_f32_16x16x32_bf16(
                    af[m], bfv[n], acc3[m][n], 0, 0, 0);
        __syncthreads();
        cur ^= 1;
    }

    // ---- LN1 over channels (f32 accs)
    float sP[4] = {0,0,0,0}, qP[4] = {0,0,0,0};
    #pragma unroll
    for (int n = 0; n < 4; ++n)
        #pragma unroll
        for (int m = 0; m < 4; ++m)
            #pragma unroll
            for (int r = 0; r < 4; ++r) {
                float v = acc3[m][n][r];
                sP[n] += v; qP[n] += v*v;
            }
    #pragma unroll
    for (int n = 0; n < 4; ++n) {
        sP[n] += __shfl_xor(sP[n], 16); sP[n] += __shfl_xor(sP[n], 32);
        qP[n] += __shfl_xor(qP[n], 16); qP[n] += __shfl_xor(qP[n], 32);
    }
    if (ly == 0) {
        #pragma unroll
        for (int n = 0; n < 4; ++n) {
            sredS[w][n*16 + lx] = sP[n];
            sredQ[w][n*16 + lx] = qP[n];
        }
    }
    __syncthreads();
    if (t < 64) {
        float s = 0.f, q = 0.f;
        #pragma unroll
        for (int ww = 0; ww < 4; ++ww) { s += sredS[ww][t]; q += sredQ[ww][t]; }
        float m = s * (1.f/C_);
        mrM[t] = m;
        mrR[t] = rsqrtf(q*(1.f/C_) - m*m + 1e-5f);
    }
    __syncthreads();
    #pragma unroll
    for (int n = 0; n < 4; ++n) {
        float mn = mrM[n*16 + lx], rs = mrR[n*16 + lx];
        #pragma unroll
        for (int m = 0; m < 4; ++m) {
            int c0 = w*64 + m*16 + ly*4;
            bf16x4 pk;
            #pragma unroll
            for (int r = 0; r < 4; ++r) {
                int c = c0 + r;
                pk[r] = f2bf((acc3[m][n][r] - mn)*rs*gbet[c] + gbet[256 + c]);
            }
            *(bf16x4*)&QT[n*16 + lx][c0] = pk;
        }
    }
    __syncthreads();
    short* og = mrg + ((size_t)g*NS_ + l0)*C_;
    int row = t >> 2;
    #pragma unroll
    for (int i = 0; i < 8; ++i) {
        int chk = (t & 3) + 4*i;
        *(uint4*)(og + (size_t)row*C_ + chk*8) = *(const uint4*)&QT[row][chk*8];
    }
}

// ---------------------------------------------------------------------------
// Fused mlp2 + LN2 + residual + transpose; round-6 proven 2-phase dbuf.
__global__ __launch_bounds__(256, 4)
void m2f_kernel(const short* __restrict__ hid, const short* __restrict__ wt2,
                const float* __restrict__ sfeat,
                const float* __restrict__ ln2g, const float* __restrict__ ln2b,
                float* __restrict__ out, int b0)
{
    __shared__ __align__(16) short sh[2*10240];  // dbuf As 8192|Bs 2048; later QTm
    __shared__ float sredS[4][64], sredQ[4][64];
    __shared__ float mrM[64], mrR[64];
    __shared__ float gbet[512];

    int g = blockIdx.y, gb = b0 + g;
    int l0 = blockIdx.x * 64;
    int t = threadIdx.x;
    int lane = t & 63, w = t >> 6;
    int lx = lane & 15, ly = lane >> 4;

    gbet[t]       = ln2g[t];
    gbet[256 + t] = ln2b[t];

    const short* hg = hid + ((size_t)g*NS_ + l0)*C2_;

    auto stage = [&](int buf, int kb) {
        short* As = sh + buf*10240;
        short* Bs = As + 8192;
        #pragma unroll
        for (int i = 0; i < 4; ++i) {
            int row = (t>>2) + 64*i;
            load_lds16(wt2 + (size_t)row*C2_ + kb + (t&3)*8, &As[row*32 + (t&3)*8]);
        }
        load_lds16(hg + (size_t)(t>>2)*C2_ + kb + (t&3)*8, &Bs[(t>>2)*32 + (t&3)*8]);
    };

    f32x4 acc[4][4] = {};
    stage(0, 0);
    __syncthreads();
    int cur = 0;
    for (int kb = 0; kb < C2_; kb += 32) {
        if (kb + 32 < C2_) stage(cur ^ 1, kb + 32);
        const short* As = sh + cur*10240;
        const short* Bs = As + 8192;
        bf16x8 af[4], bfv[4];
        #pragma unroll
        for (int m = 0; m < 4; ++m)
            af[m] = *(const bf16x8*)&As[(w*64 + m*16 + lx)*32 + ly*8];
        #pragma unroll
        for (int n = 0; n < 4; ++n)
            bfv[n] = *(const bf16x8*)&Bs[(n*16 + lx)*32 + ly*8];
        #pragma unroll
        for (int m = 0; m < 4; ++m)
            #pragma unroll
            for (int n = 0; n < 4; ++n)
                acc[m][n] = __builtin_amdgcn_mfma_f32_16x16x32_bf16(
                    af[m], bfv[n], acc[m][n], 0, 0, 0);
        __syncthreads();
        cur ^= 1;
    }

    // LN2 reduction over channels (f32 accs)
    float sP[4] = {0,0,0,0}, qP[4] = {0,0,0,0};
    #pragma unroll
    for (int n = 0; n < 4; ++n)
        #pragma unroll
        for (int m = 0; m < 4; ++m)
            #pragma unroll
            for (int r = 0; r < 4; ++r) {
                float v = acc[m][n][r];
                sP[n] += v; qP[n] += v*v;
            }
    #pragma unroll
    for (int n = 0; n < 4; ++n) {
        sP[n] += __shfl_xor(sP[n], 16); sP[n] += __shfl_xor(sP[n], 32);
        qP[n] += __shfl_xor(qP[n], 16); qP[n] += __shfl_xor(qP[n], 32);
    }
    if (ly == 0) {
        #pragma unroll
        for (int n = 0; n < 4; ++n) {
            sredS[w][n*16 + lx] = sP[n];
            sredQ[w][n*16 + lx] = qP[n];
        }
    }
    __syncthreads();
    if (t < 64) {
        float s = 0.f, q = 0.f;
        #pragma unroll
        for (int ww = 0; ww < 4; ++ww) { s += sredS[ww][t]; q += sredQ[ww][t]; }
        float m = s * (1.f/C_);
        mrM[t] = m;
        mrR[t] = rsqrtf(q*(1.f/C_) - m*m + 1e-5f);
    }
    __syncthreads();

    // pack normalized bf16 into QTm (overlays staging; dead)
    #pragma unroll
    for (int n = 0; n < 4; ++n) {
        int l = n*16 + lx;
        float mn = mrM[l], rs = mrR[l];
        #pragma unroll
        for (int m = 0; m < 4; ++m) {
            int c0 = w*64 + m*16 + ly*4;
            #pragma unroll
            for (int r = 0; r < 4; ++r)
                sh[l*258 + c0 + r] =
                    f2bf((acc[m][n][r] - mn)*rs*gbet[c0+r] + gbet[256 + c0 + r]);
        }
    }
    __syncthreads();

    // coalesced residual + f32 store
    int l = t & 63, cg = t >> 6;
    const float* sfp = sfeat + (size_t)gb*C_*NS_ + l0;
    float* op = out + (size_t)gb*C_*NS_ + l0;
    for (int ci = 0; ci < 64; ++ci) {
        int c = cg*64 + ci;
        size_t o = (size_t)c*NS_ + l;
        op[o] = sfp[o] + bf2f(sh[l*258 + c]);
    }
}

// ---------------------------------------------------------------------------
extern "C" void kernel_launch(void* const* d_in, const int* in_sizes, int n_in,
                              void* d_out, int out_size, void* d_ws, size_t ws_size,
                              hipStream_t stream)
{
    (void)in_sizes; (void)n_in; (void)out_size;
    const float* search_feat   = (const float*)d_in[0];
    const float* template_feat = (const float*)d_in[2];
    const float* template_xyz  = (const float*)d_in[3];
    const float* pos_w1  = (const float*)d_in[4];
    const float* pos_b1  = (const float*)d_in[5];
    const float* pos_w2  = (const float*)d_in[6];
    const float* pos_b2  = (const float*)d_in[7];
    const float* q_w     = (const float*)d_in[8];
    const float* k_w     = (const float*)d_in[9];
    const float* v_w     = (const float*)d_in[10];
    const float* merge_w = (const float*)d_in[11];
    const float* mlp_w1  = (const float*)d_in[12];
    const float* mlp_w2  = (const float*)d_in[13];
    const float* ln1_g   = (const float*)d_in[14];
    const float* ln1_b   = (const float*)d_in[15];
    const float* ln2_g   = (const float*)d_in[16];
    const float* ln2_b   = (const float*)d_in[17];
    float* out = (float*)d_out;

    const int W_Q = 0, W_K = 65536, W_M = 131072, W_P = 196608,
              W_1 = 262144, W_2 = 524288, W_V2 = 655360;
    const size_t wElems = 786432;

    size_t sfE = (size_t)NS_*C_, tfE = (size_t)NT_*C_;
    int G = 8;
    while (G > 1) {
        size_t shorts = (size_t)G*(4*sfE + tfE + 8192) + wElems;
        size_t bytes  = shorts*2 + (size_t)G*(NCH*KVZ_ + 256)*4 + 256*4 + 1024;
        if (bytes <= ws_size) break;
        G >>= 1;
    }

    short* wtb  = (short*)d_ws;
    short* sfb  = wtb  + wElems;          // [G,NS,C]
    short* tfb  = sfb  + (size_t)G*sfE;   // [G,NT,C]
    short* hid  = tfb  + (size_t)G*tfE;   // [G,NS,2C]; early: K | V | h
    short* mrgb = hid  + (size_t)2*G*sfE; // [G,NS,C]  LN1(merge) out
    short* KVTb = mrgb + (size_t)G*sfE;   // [G,8192]
    float* kvpf = (float*)(KVTb + (size_t)G*8192);
    float* KSfb = kvpf + (size_t)G*NCH*KVZ_;
    float* bvf  = KSfb + (size_t)G*256;
    short* Kb = hid;
    short* Vb = hid + (size_t)G*tfE;
    short* hb = hid + (size_t)2*G*tfE;    // pos-mlp hidden h [G,NT,C]

    WPack pack;
    pack.d[0] = { q_w,     C_,  C_,  W_Q,  C_  };
    pack.d[1] = { k_w,     C_,  C_,  W_K,  C_  };
    pack.d[2] = { merge_w, C_,  C_,  W_M,  C_  };
    pack.d[3] = { pos_w2,  C_,  C_,  W_P,  C_  };
    pack.d[4] = { mlp_w1,  C2_, C2_, W_1,  C2_ };
    pack.d[5] = { mlp_w2,  C2_, C_,  W_2,  C2_ };
    pack.d[6] = { v_w,     C_,  C_,  W_V2, C2_ };  // first half of fused V
    wcast_all<<<dim3(16, 16, 7), 256, 0, stream>>>(pack, wtb);
    fusew<<<dim3(256), 256, 0, stream>>>(wtb + W_V2, wtb + W_P, pos_b2, v_w, bvf);

    for (int b0 = 0; b0 < B_; b0 += G) {
        castT<<<dim3(NS_/32, C_/32, G), 256, 0, stream>>>(search_feat, sfb, NS_, b0);
        castT<<<dim3(NT_/32, C_/32, G), 256, 0, stream>>>(template_feat, tfb, NT_, b0);
        pos_h<<<dim3(NT_/16, G), 256, 0, stream>>>(template_xyz, pos_w1, pos_b1, hb, b0);
        // K = elu(tf @ k_w)+1
        gemm_bf16<2,4><<<dim3(C_/128, NT_/128, G), 256, 0, stream>>>(
            tfb, C_, nullptr, 0, 1<<30, wtb + W_K, nullptr, Kb, NT_, C_, C_);
        // V = [tf | h] @ [v_w ; posw2@v_w] + (b2@v_w)
        gemm_bf16<4,4><<<dim3(C_/128, NT_/128, G), 256, 0, stream>>>(
            tfb, C_, hb, C_, C_, wtb + W_V2, bvf, Vb, NT_, C_, C2_);
        kv_kernel<<<dim3(H_, NCH, G), 256, 0, stream>>>(Kb, Vb, kvpf);
        kvfin<<<dim3(G), 256, 0, stream>>>(kvpf, KVTb, KSfb);
        // fused Q -> attn -> merge -> LN1
        qam_kernel<<<dim3(NS_/64, G), 256, 0, stream>>>(
            sfb, wtb + W_Q, wtb + W_M, KVTb, KSfb, ln1_g, ln1_b, mrgb);
        // hidden = relu([sf | mrg] @ mlp_w1)
        gemm_bf16<1,4><<<dim3(C2_/128, NS_/128, G), 256, 0, stream>>>(
            sfb, C_, mrgb, C_, C_, wtb + W_1, nullptr, hid, NS_, C2_, C2_);
        // fused mlp2 + LN2 + residual + transpose
        m2f_kernel<<<dim3(NS_/64, G), 256, 0, stream>>>(
            hid, wtb + W_2, search_feat, ln2_g, ln2_b, out, b0);
    }
}